// Round 12
// baseline (244.805 us; speedup 1.0000x reference)
//
#include <hip/hip_runtime.h>
#include <hip/hip_bf16.h>
#include <math.h>

#define BATCH 512
#define N_NODES 116
#define IN_DIM 123
#define HID 128
#define HEADS 4
#define FLAT_DIM 1280

static constexpr int BN_TOT = BATCH * N_NODES;      // 59392
static constexpr int HROW = N_NODES * HID;          // 14848

typedef short short8 __attribute__((ext_vector_type(8)));
typedef float f32x16 __attribute__((ext_vector_type(16)));

__device__ __forceinline__ float elu1(float x) {
    return x > 0.f ? x : __expf(x) - 1.f;
}
__device__ __forceinline__ short bfb(float x) {
    __hip_bfloat16 b = __float2bfloat16(x);
    return *reinterpret_cast<short*>(&b);
}
__device__ __forceinline__ float bf2f(short s) {
    return __bfloat162float(*reinterpret_cast<__hip_bfloat16*>(&s));
}

// ---------------- x prep: f32 [row][123] -> bf16 [row][128] zero-pad ------
__global__ __launch_bounds__(256) void xprep_kernel(
    const float* __restrict__ x, short* __restrict__ xb)
{
    const int idx = blockIdx.x * 256 + threadIdx.x;
    const int row = idx >> 7, k = idx & 127;
    xb[idx] = (k < IN_DIM) ? bfb(x[(size_t)row * IN_DIM + k]) : (short)0;
}

// ---------------- W_enc prep: bf16 [col][k=128] zero-pad ------------------
__global__ __launch_bounds__(256) void wencprep_kernel(
    const float* __restrict__ W, short* __restrict__ Wb)
{
    const int idx = blockIdx.x * 256 + threadIdx.x;  // 0..16383
    const int col = idx >> 7, k = idx & 127;
    Wb[idx] = (k < IN_DIM) ? bfb(W[(size_t)k * HID + col]) : (short)0;
}

// ---------------- encoder via MFMA: h = BN(elu(xb @ Wencb + b)) -----------
__global__ __launch_bounds__(256) void enc_mfma(
    const short* __restrict__ xb, const short* __restrict__ Wencb,
    const float* __restrict__ bias,
    const float* __restrict__ g, const float* __restrict__ bta,
    const float* __restrict__ mn, const float* __restrict__ vr,
    float* __restrict__ hout)
{
    const int t = threadIdx.x;
    const int lane = t & 63, w = t >> 6;
    const int half = lane >> 5, nn = lane & 31;
    const int row0 = blockIdx.x * 128 + w * 32;
    const short8* ap = reinterpret_cast<const short8*>(xb + (size_t)(row0 + nn) * 128);
    short8 af[8];
#pragma unroll
    for (int s = 0; s < 8; ++s) af[s] = ap[s * 2 + half];
#pragma unroll
    for (int ct = 0; ct < 4; ++ct) {
        const int col = ct * 32 + nn;
        const short8* bp = reinterpret_cast<const short8*>(Wencb + (size_t)col * 128);
        f32x16 acc = {};
#pragma unroll
        for (int s = 0; s < 8; ++s)
            acc = __builtin_amdgcn_mfma_f32_32x32x16_bf16(af[s], bp[s * 2 + half], acc, 0, 0, 0);
        const float bb = bias[col];
        const float gg = g[col], bbn = bta[col], mm = mn[col];
        const float rstd = rsqrtf(vr[col] + 1e-5f);
#pragma unroll
        for (int reg = 0; reg < 16; ++reg) {
            const int r = (reg & 3) + 8 * (reg >> 2) + 4 * half;
            float val = elu1(acc[reg] + bb);
            val = (val - mm) * rstd * gg + bbn;
            hout[(size_t)(row0 + r) * HID + col] = val;
        }
    }
}

// ---------------- weight prep: Wt bf16 [h][nn][k] + Weij bf16 -------------
__global__ __launch_bounds__(256) void wprep_kernel(
    const float* __restrict__ W, const float* __restrict__ a,
    short* __restrict__ Wt, short* __restrict__ Weij)
{
    const int idx = blockIdx.x * 256 + threadIdx.x;  // 0..16383
    const int h = idx >> 12, nn = (idx >> 7) & 31, k = idx & 127;
    Wt[idx] = bfb(W[k * HID + h * 32 + nn]);
    short wv = 0;
    if (nn < 2) {
        const float* ap = a + h * 64 + nn * 32;
        float s = 0.f;
#pragma unroll 8
        for (int d = 0; d < 32; ++d) s += W[k * HID + h * 32 + d] * ap[d];
        wv = bfb(s);
    }
    Weij[idx] = wv;
}

// ---------------- classifier weight prep: wc1t bf16 [n][k] ----------------
__global__ __launch_bounds__(256) void wc1prep_kernel(
    const float* __restrict__ Wc1, short* __restrict__ wc1t)
{
    const int idx = blockIdx.x * 256 + threadIdx.x;  // n fastest
    const int k = idx >> 8, n = idx & 255;
    wc1t[(size_t)n * FLAT_DIM + k] = bfb(Wc1[(size_t)k * 256 + n]);
}

// ---------------- adj bit-pack: one wave per (b,i) row --------------------
__global__ __launch_bounds__(256) void adjpack_kernel(
    const float* __restrict__ adj, unsigned int* __restrict__ adjp)
{
    const int row = blockIdx.x * 4 + (threadIdx.x >> 6);  // b*116+i
    const int l = threadIdx.x & 63;
    const float a1 = adj[(size_t)row * N_NODES + l];
    const float a2 = (l < N_NODES - 64) ? adj[(size_t)row * N_NODES + 64 + l] : 0.f;
    const unsigned long long m1 = __ballot(a1 != 0.f);
    const unsigned long long m2 = __ballot(a2 != 0.f);
    if (l == 0) {
        uint4 v;
        v.x = (unsigned int)m1; v.y = (unsigned int)(m1 >> 32);
        v.z = (unsigned int)m2; v.w = (unsigned int)(m2 >> 32);
        *reinterpret_cast<uint4*>(&adjp[(size_t)row * 4]) = v;
    }
}

// ---------------- vn0 = vne + mean_n(h) ----------------
__global__ __launch_bounds__(128) void vn0_kernel(
    const float* __restrict__ h, const float* __restrict__ vne,
    float* __restrict__ vn)
{
    const int b = blockIdx.x, f = threadIdx.x;
    float s = 0.f;
    for (int n = 0; n < N_NODES; ++n) s += h[(size_t)b * HROW + n * HID + f];
    vn[b * HID + f] = vne[f] + s * (1.f / N_NODES);
}

// ---------------- MEGA: gat1 + vn_mlp + gat2 + vn_mlp, one block/batch ----
__global__ __launch_bounds__(256, 3) void gat_mega(
    float* __restrict__ hA,              // in: enc h (f32); out: final h (f32)
    short* __restrict__ hb1,             // scratch bf16 [BN_TOT][128]
    const short* __restrict__ Wt1, const short* __restrict__ We1,
    const short* __restrict__ Wt2, const short* __restrict__ We2,
    const uint4* __restrict__ adjp4,
    const float* __restrict__ g1, const float* __restrict__ bt1,
    const float* __restrict__ m1, const float* __restrict__ v1,
    const float* __restrict__ g2, const float* __restrict__ bt2,
    const float* __restrict__ m2, const float* __restrict__ v2,
    const float* __restrict__ vn0g, const float* __restrict__ Wv,
    const float* __restrict__ bv, float* __restrict__ vnfg)
{
    constexpr int KP = 136;  // s_p pitch (shorts), proven conflict-free
    constexpr int WP = 33;
    __shared__ __align__(16) __hip_bfloat16 s_p[N_NODES][KP];   // 31552 B
    __shared__ __align__(16) __hip_bfloat16 s_whsb[128][WP];    // 8448 B
    __shared__ uint4 s_adj[N_NODES];                            // 1856 B
    __shared__ float s_eir[232];                                // 928 B
    __shared__ float s_vn[128];                                 // 512 B
    __shared__ float s_pm[128];                                 // 512 B
    __shared__ float s_red[128];                                // 512 B -> 44320 B

    const int t = threadIdx.x;
    const int b = blockIdx.x;
    const int lane = t & 63, w = t >> 6;
    const int half = lane >> 5, nn = lane & 31;
    const int row = w * 32 + nn;
    const int hr = (row < N_NODES) ? row : 0;

    // stage adj masks + vn0 (visible after first head barrier)
    if (t < N_NODES) s_adj[t] = adjp4[(size_t)b * N_NODES + t];
    if (t < 128) s_vn[t] = vn0g[(size_t)b * 128 + t];

    // layer-1 A-fragments from global f32 h (once per block)
    short8 af[8];
    {
        const float* hrow = hA + ((size_t)b * N_NODES + hr) * HID;
#pragma unroll
        for (int s = 0; s < 8; ++s) {
            const int k0 = s * 16 + half * 8;
            const float4 x0 = *reinterpret_cast<const float4*>(&hrow[k0]);
            const float4 x1 = *reinterpret_cast<const float4*>(&hrow[k0 + 4]);
            short8 fr;
            fr[0] = bfb(x0.x); fr[1] = bfb(x0.y); fr[2] = bfb(x0.z); fr[3] = bfb(x0.w);
            fr[4] = bfb(x1.x); fr[5] = bfb(x1.y); fr[6] = bfb(x1.z); fr[7] = bfb(x1.w);
            af[s] = fr;
        }
    }

    for (int L = 0; L < 2; ++L) {
        const short* Wt = L ? Wt2 : Wt1;
        const short* We = L ? We2 : We1;
        const float* g_ = L ? g2 : g1;   const float* bt_ = L ? bt2 : bt1;
        const float* mn_ = L ? m2 : m1;  const float* vr_ = L ? v2 : v1;

        for (int h = 0; h < HEADS; ++h) {
            // ---- p1: Whs + [ei|ej] via MFMA (registers/global only) ----
            const short8* wtp = reinterpret_cast<const short8*>(Wt + ((h * 32 + nn) << 7));
            const short8* wep = reinterpret_cast<const short8*>(We + ((h * 32 + nn) << 7));
            f32x16 wacc = {};
            f32x16 eacc = {};
#pragma unroll
            for (int s = 0; s < 8; ++s) {
                const int fi = s * 2 + half;
                wacc = __builtin_amdgcn_mfma_f32_32x32x16_bf16(af[s], wtp[fi], wacc, 0, 0, 0);
                eacc = __builtin_amdgcn_mfma_f32_32x32x16_bf16(af[s], wep[fi], eacc, 0, 0, 0);
            }
            __syncthreads();   // prior head's p3/premean LDS reads complete
#pragma unroll
            for (int reg = 0; reg < 16; ++reg) {
                const int r = (reg & 3) + 8 * (reg >> 2) + 4 * half;
                s_whsb[w * 32 + r][nn] = __float2bfloat16(wacc[reg]);
            }
            if (nn == 0) {
#pragma unroll
                for (int reg = 0; reg < 16; ++reg) {
                    const int r = w * 32 + (reg & 3) + 8 * (reg >> 2) + 4 * half;
                    if (r < N_NODES) s_eir[r] = eacc[reg];
                }
            }
            if (nn == 1) {
#pragma unroll
                for (int reg = 0; reg < 16; ++reg) {
                    const int r = w * 32 + (reg & 3) + 8 * (reg >> 2) + 4 * half;
                    if (r < N_NODES) s_eir[N_NODES + r] = eacc[reg];
                }
            }
            __syncthreads();   // scatter visible

            // ---- p2 (wave-local rows): unnormalized exp scores ----
            {
                const int l = lane;
                const float ejl = s_eir[N_NODES + l];
                const bool up = (l < N_NODES - 64);
                const float ejl2 = up ? s_eir[N_NODES + l + 64] : 0.f;
                const int i0 = w * 32;
                const int cnt = min(32, N_NODES - i0);
                for (int ii = 0; ii < cnt; ++ii) {
                    const int i = i0 + ii;
                    const uint4 aw = s_adj[i];   // broadcast LDS read
                    const float eii = s_eir[i];
                    const unsigned int w1 = (l & 32) ? aw.y : aw.x;
                    const unsigned int w2 = (l & 32) ? aw.w : aw.z;
                    const bool bit1 = (w1 >> (l & 31)) & 1;
                    const bool bit2 = (w2 >> (l & 31)) & 1;
                    float e1 = eii + ejl;
                    e1 = e1 > 0.f ? e1 : 0.2f * e1;
                    const float x1 = bit1 ? __expf(e1) : 0.f;
                    float x2 = 0.f;
                    if (up) {
                        float e2 = eii + ejl2;
                        e2 = e2 > 0.f ? e2 : 0.2f * e2;
                        x2 = bit2 ? __expf(e2) : 0.f;
                    }
                    s_p[i][l] = __float2bfloat16(x1);
                    s_p[i][l + 64] = __float2bfloat16(x2);  // zeros A K-pad
                }
            }
            // no barrier: p3 reads only this wave's s_p rows

            // ---- p3: O = P_u @ Whs, rowsum = P_u @ ones ----
            float psum = 0.f;
            {
                f32x16 acc = {};
                f32x16 accs = {};
                short8 ones;
#pragma unroll
                for (int e = 0; e < 8; ++e) ones[e] = (short)0x3F80;
#pragma unroll
                for (int s = 0; s < 8; ++s) {
                    const int k0 = s * 16 + half * 8;
                    const short8 afr = *reinterpret_cast<const short8*>(
                        &s_p[0][0] + (size_t)row * KP + k0);
                    short8 bfr;
#pragma unroll
                    for (int e = 0; e < 8; ++e)
                        bfr[e] = *reinterpret_cast<const short*>(&s_whsb[k0 + e][nn]);
                    acc = __builtin_amdgcn_mfma_f32_32x32x16_bf16(afr, bfr, acc, 0, 0, 0);
                    accs = __builtin_amdgcn_mfma_f32_32x32x16_bf16(afr, ones, accs, 0, 0, 0);
                }
                const int f = h * 32 + nn;
                const float G = g_[f], B = bt_[f], M = mn_[f];
                const float R = rsqrtf(vr_[f] + 1e-5f);
#pragma unroll
                for (int reg = 0; reg < 16; ++reg) {
                    const int r = (reg & 3) + 8 * (reg >> 2) + 4 * half;
                    const int i = w * 32 + r;
                    if (i < N_NODES) {
                        const size_t off = ((size_t)b * N_NODES + i) * HID + f;
                        const float aval = acc[reg] / accs[reg];
                        float xv = elu1((aval - M) * R * G + B);
                        float outv = xv + bf2f(*reinterpret_cast<const short*>(&s_whsb[i][nn]));
                        if (L == 1) {
                            outv += bf2f(hb1[off]) + 0.1f * s_vn[f];
                            hA[off] = outv;
                        } else {
                            hb1[off] = bfb(outv);
                        }
                        psum += outv;
                    }
                }
            }
            psum += __shfl_xor(psum, 32);
            if (half == 0) s_red[w * 32 + nn] = psum;
            __syncthreads();   // s_red visible; also all p3 s_p/s_whsb reads done
            if (t < 32)
                s_pm[h * 32 + t] = (s_red[t] + s_red[32 + t] + s_red[64 + t]
                                    + s_red[96 + t]) * (1.f / N_NODES);
        }  // heads

        __syncthreads();   // s_pm complete
        // ---- vn MLP: vnn (L=0) or vnf (L=1) ----
        float vval = 0.f;
        if (t < 128) {
            float acc2 = bv[t];
#pragma unroll 4
            for (int k = 0; k < 128; ++k) acc2 += s_vn[k] * Wv[k * HID + t];
#pragma unroll 4
            for (int k = 0; k < 128; ++k) acc2 += s_pm[k] * Wv[(128 + k) * HID + t];
            vval = elu1(acc2);
        }
        __syncthreads();
        if (L == 0) {
            if (t < 128) s_vn[t] = vval;   // vnn
            __syncthreads();
            // rebuild A-frags: af = bf16(h1 + 0.1*vnn) from hb1 (L2-hot)
            const short* hbrow = hb1 + ((size_t)b * N_NODES + hr) * HID;
#pragma unroll
            for (int s = 0; s < 8; ++s) {
                const int k0 = s * 16 + half * 8;
                const short8 v = *reinterpret_cast<const short8*>(&hbrow[k0]);
                short8 fr;
#pragma unroll
                for (int e = 0; e < 8; ++e)
                    fr[e] = bfb(bf2f(v[e]) + 0.1f * s_vn[k0 + e]);
                af[s] = fr;
            }
        } else {
            if (t < 128) vnfg[(size_t)b * HID + t] = vval;
        }
    }  // layers
}

// ---------------- pooling + net attention + flat + LayerNorm --------------
__global__ __launch_bounds__(128) void pool_flat_kernel(
    const float* __restrict__ h, const float* __restrict__ vnf,
    const float* __restrict__ pm,
    const float* __restrict__ Wa1, const float* __restrict__ ba1,
    const float* __restrict__ Wa2, const float* __restrict__ ba2,
    const float* __restrict__ ln_g, const float* __restrict__ ln_b,
    float* __restrict__ out, short* __restrict__ flatb)
{
    __shared__ float s_pm[N_NODES * 9];
    __shared__ float s_p[9][HID];
    __shared__ float s_s[9];
    __shared__ float s_red[4];
    const int b = blockIdx.x, f = threadIdx.x;
    for (int idx = f; idx < N_NODES * 9; idx += 128) s_pm[idx] = pm[idx];
    float p[9] = {};
    __syncthreads();
    for (int n = 0; n < N_NODES; ++n) {
        const float hv = h[(size_t)b * HROW + n * HID + f];
#pragma unroll
        for (int k = 0; k < 9; ++k) p[k] += s_pm[n * 9 + k] * hv;
    }
#pragma unroll
    for (int k = 0; k < 9; ++k) s_p[k][f] = p[k];
    __syncthreads();
    for (int pass = 0; pass < 3; ++pass) {
        const int k = pass * 4 + (f >> 5);
        if (k < 9) {
            const int j = f & 31;
            float z = ba1[j];
            for (int d = 0; d < HID; ++d) z += s_p[k][d] * Wa1[d * 32 + j];
            z = tanhf(z);
            float part = z * Wa2[j];
#pragma unroll
            for (int off = 16; off; off >>= 1) part += __shfl_xor(part, off);
            if (j == 0) s_s[k] = part + ba2[0];
        }
    }
    __syncthreads();
    float smax = -1e30f;
#pragma unroll
    for (int k = 0; k < 9; ++k) smax = fmaxf(smax, s_s[k]);
    float wgt[9], ssum = 0.f;
#pragma unroll
    for (int k = 0; k < 9; ++k) { wgt[k] = expf(s_s[k] - smax); ssum += wgt[k]; }
    const float sinv = 1.f / ssum;
    float vals[10];
#pragma unroll
    for (int k = 0; k < 9; ++k) vals[k] = p[k] * wgt[k] * sinv;
    vals[9] = vnf[b * HID + f];
    float lsum = 0.f, lsq = 0.f;
#pragma unroll
    for (int q = 0; q < 10; ++q) { lsum += vals[q]; lsq += vals[q] * vals[q]; }
#pragma unroll
    for (int off = 32; off; off >>= 1) {
        lsum += __shfl_xor(lsum, off);
        lsq += __shfl_xor(lsq, off);
    }
    const int lane = f & 63, wid = f >> 6;
    if (lane == 0) { s_red[wid * 2] = lsum; s_red[wid * 2 + 1] = lsq; }
    __syncthreads();
    const float tot = s_red[0] + s_red[2];
    const float totsq = s_red[1] + s_red[3];
    const float mean = tot * (1.f / FLAT_DIM);
    const float var = totsq * (1.f / FLAT_DIM) - mean * mean;
    const float rstd = rsqrtf(var + 1e-5f);
    float* fout = out + 1024 + (size_t)b * FLAT_DIM;
    short* fb = flatb + (size_t)b * FLAT_DIM;
#pragma unroll
    for (int k = 0; k < 9; ++k) {
        const int j = k * HID + f;
        const float v = (vals[k] - mean) * rstd * ln_g[j] + ln_b[j];
        fout[j] = v;
        fb[j] = bfb(v);
    }
    const int j = 9 * HID + f;
    const float v9 = (vals[9] - mean) * rstd * ln_g[j] + ln_b[j];
    fout[j] = v9;
    fb[j] = bfb(v9);
}

// ---------------- classifier stage 1: hid = elu(flat @ Wc1 + bc1), MFMA ---
__global__ __launch_bounds__(256) void cls_mm_kernel(
    const short* __restrict__ flatb, const short* __restrict__ wc1t,
    const float* __restrict__ bc1, float* __restrict__ hid)
{
    const int t = threadIdx.x;
    const int lane = t & 63, w = t >> 6;
    const int half = lane >> 5, nn = lane & 31;
    const int mt = blockIdx.x >> 1;
    const int nh = blockIdx.x & 1;
    const int r0 = mt * 32;
    const int c0 = nh * 128 + w * 32;
    const short8* ap = reinterpret_cast<const short8*>(flatb + (size_t)(r0 + nn) * FLAT_DIM);
    const short8* bp = reinterpret_cast<const short8*>(wc1t + (size_t)(c0 + nn) * FLAT_DIM);
    f32x16 acc = {};
#pragma unroll 8
    for (int s = 0; s < 80; ++s) {
        const int fi = s * 2 + half;
        acc = __builtin_amdgcn_mfma_f32_32x32x16_bf16(ap[fi], bp[fi], acc, 0, 0, 0);
    }
    const float bb = bc1[c0 + nn];
#pragma unroll
    for (int reg = 0; reg < 16; ++reg) {
        const int row = (reg & 3) + 8 * (reg >> 2) + 4 * half;
        hid[(size_t)(r0 + row) * 256 + c0 + nn] = elu1(acc[reg] + bb);
    }
}

// ---------------- classifier stage 2: logits = hid @ Wc2 + bc2 (f32) ------
__global__ __launch_bounds__(256) void logits_kernel(
    const float* __restrict__ hid, const float* __restrict__ Wc2,
    const float* __restrict__ bc2, float* __restrict__ out)
{
    const int idx = blockIdx.x * 256 + threadIdx.x;  // 0..1023
    const int row = idx >> 1, c = idx & 1;
    const float4* hp = reinterpret_cast<const float4*>(hid + (size_t)row * 256);
    float acc = 0.f;
#pragma unroll 8
    for (int q = 0; q < 64; ++q) {
        const float4 hv = hp[q];
        acc += hv.x * Wc2[(q * 4 + 0) * 2 + c] + hv.y * Wc2[(q * 4 + 1) * 2 + c]
             + hv.z * Wc2[(q * 4 + 2) * 2 + c] + hv.w * Wc2[(q * 4 + 3) * 2 + c];
    }
    out[idx] = acc + bc2[c];
}

extern "C" void kernel_launch(void* const* d_in, const int* in_sizes, int n_in,
                              void* d_out, int out_size, void* d_ws, size_t ws_size,
                              hipStream_t stream)
{
    const float* x     = (const float*)d_in[0];
    const float* adj   = (const float*)d_in[1];
    const float* W_enc = (const float*)d_in[2];
    const float* b_enc = (const float*)d_in[3];
    const float* bn_g  = (const float*)d_in[4];
    const float* bn_b  = (const float*)d_in[5];
    const float* bn_m  = (const float*)d_in[6];
    const float* bn_v  = (const float*)d_in[7];
    const float* vne   = (const float*)d_in[8];
    const float* W1    = (const float*)d_in[9];
    const float* a1    = (const float*)d_in[10];
    const float* g1    = (const float*)d_in[11];
    const float* bt1   = (const float*)d_in[12];
    const float* m1    = (const float*)d_in[13];
    const float* v1    = (const float*)d_in[14];
    const float* W2    = (const float*)d_in[15];
    const float* a2    = (const float*)d_in[16];
    const float* g2    = (const float*)d_in[17];
    const float* bt2   = (const float*)d_in[18];
    const float* m2    = (const float*)d_in[19];
    const float* v2    = (const float*)d_in[20];
    const float* Wv    = (const float*)d_in[21];
    const float* bv    = (const float*)d_in[22];
    const float* pm    = (const float*)d_in[23];
    const float* Wa1   = (const float*)d_in[24];
    const float* ba1   = (const float*)d_in[25];
    const float* Wa2   = (const float*)d_in[26];
    const float* ba2   = (const float*)d_in[27];
    const float* ln_g  = (const float*)d_in[28];
    const float* ln_b  = (const float*)d_in[29];
    const float* Wc1   = (const float*)d_in[30];
    const float* bc1   = (const float*)d_in[31];
    const float* Wc2   = (const float*)d_in[32];
    const float* bc2   = (const float*)d_in[33];
    float* out = (float*)d_out;

    float* ws = (float*)d_ws;
    float* hA   = ws;                                 // 7,602,176 floats
    float* hB   = hA + (size_t)BN_TOT * HID;          // 7,602,176 (scratch region)
    float* vn0g = hB + (size_t)BN_TOT * HID;
    float* vnfg = vn0g + BATCH * HID;
    unsigned int* adjp = (unsigned int*)(vnfg + BATCH * HID);  // 237,568 uints
    short* Wt1  = (short*)(adjp + (size_t)BN_TOT * 4);         // 16384 shorts each
    short* We1  = Wt1 + 16384;
    short* Wt2  = We1 + 16384;
    short* We2  = Wt2 + 16384;
    short* Wencb = We2 + 16384;                                // 16384 shorts
    // transient aliases inside hB:
    short* xb    = (short*)hB;                        // dead after enc_mfma
    short* hb1   = (short*)hB;                        // inter-layer h (bf16), dead after gat_mega
    short* flatb = (short*)hB;                        // classifier scratch (after gat_mega)
    short* wc1t  = flatb + (size_t)BATCH * FLAT_DIM;
    float* hid   = (float*)(wc1t + 256 * FLAT_DIM);

    // prep: bf16 weights + folded attention vectors + packed adjacency + x
    wprep_kernel<<<64, 256, 0, stream>>>(W1, a1, Wt1, We1);
    wprep_kernel<<<64, 256, 0, stream>>>(W2, a2, Wt2, We2);
    wencprep_kernel<<<64, 256, 0, stream>>>(W_enc, Wencb);
    adjpack_kernel<<<BN_TOT / 4, 256, 0, stream>>>(adj, adjp);
    xprep_kernel<<<BN_TOT * 128 / 256, 256, 0, stream>>>(x, xb);

    // encoder via MFMA: xb(=hB) -> hA
    enc_mfma<<<BN_TOT / 128, 256, 0, stream>>>(xb, Wencb, b_enc, bn_g, bn_b,
                                               bn_m, bn_v, hA);
    vn0_kernel<<<BATCH, 128, 0, stream>>>(hA, vne, vn0g);
    // fused gat1 + vn_mlp + gat2 + vn_mlp: hA -> hA (hb1 = bf16 inter-layer)
    gat_mega<<<BATCH, 256, 0, stream>>>(
        hA, hb1, Wt1, We1, Wt2, We2, (const uint4*)adjp,
        g1, bt1, m1, v1, g2, bt2, m2, v2, vn0g, Wv, bv, vnfg);
    // classifier weight prep into hB (hb1 dead now)
    wc1prep_kernel<<<1280, 256, 0, stream>>>(Wc1, wc1t);
    // pooling + flat + LayerNorm (writes out[1024:] and flatb)
    pool_flat_kernel<<<BATCH, 128, 0, stream>>>(hA, vnfg, pm, Wa1, ba1, Wa2, ba2,
                                                ln_g, ln_b, out, flatb);
    // classifier: MFMA GEMM + tiny logits pass (writes out[0:1024])
    cls_mm_kernel<<<32, 256, 0, stream>>>(flatb, wc1t, bc1, hid);
    logits_kernel<<<4, 256, 0, stream>>>(hid, Wc2, bc2, out);
}

// Round 13
// 219.189 us; speedup vs baseline: 1.1169x; 1.1169x over previous
//
#include <hip/hip_runtime.h>
#include <hip/hip_bf16.h>
#include <math.h>

#define BATCH 512
#define N_NODES 116
#define IN_DIM 123
#define HID 128
#define HEADS 4
#define FLAT_DIM 1280

static constexpr int BN_TOT = BATCH * N_NODES;      // 59392
static constexpr int HROW = N_NODES * HID;          // 14848

typedef short short8 __attribute__((ext_vector_type(8)));
typedef float f32x16 __attribute__((ext_vector_type(16)));

__device__ __forceinline__ float elu1(float x) {
    return x > 0.f ? x : __expf(x) - 1.f;
}
__device__ __forceinline__ short bfb(float x) {
    __hip_bfloat16 b = __float2bfloat16(x);
    return *reinterpret_cast<short*>(&b);
}
__device__ __forceinline__ float bf2f(short s) {
    return __bfloat162float(*reinterpret_cast<__hip_bfloat16*>(&s));
}

// ---------------- merged prep: Wt/Weij x2, Wencb, adjpack, xprep ----------
__global__ __launch_bounds__(256) void prep_all(
    const float* __restrict__ x, const float* __restrict__ adj,
    const float* __restrict__ W_enc,
    const float* __restrict__ W1, const float* __restrict__ a1,
    const float* __restrict__ W2, const float* __restrict__ a2,
    short* __restrict__ xb, unsigned int* __restrict__ adjp,
    short* __restrict__ Wencb,
    short* __restrict__ Wt1, short* __restrict__ We1,
    short* __restrict__ Wt2, short* __restrict__ We2)
{
    const int blk = blockIdx.x, t = threadIdx.x;
    if (blk < 128) {
        // wprep for layer 1 (blk<64) or layer 2
        const float* W = (blk < 64) ? W1 : W2;
        const float* a = (blk < 64) ? a1 : a2;
        short* Wt = (blk < 64) ? Wt1 : Wt2;
        short* We = (blk < 64) ? We1 : We2;
        const int idx = (blk & 63) * 256 + t;          // 0..16383
        const int h = idx >> 12, nn = (idx >> 7) & 31, k = idx & 127;
        Wt[idx] = bfb(W[k * HID + h * 32 + nn]);
        short wv = 0;
        if (nn < 2) {
            const float* ap = a + h * 64 + nn * 32;
            float s = 0.f;
#pragma unroll 8
            for (int d = 0; d < 32; ++d) s += W[k * HID + h * 32 + d] * ap[d];
            wv = bfb(s);
        }
        We[idx] = wv;
    } else if (blk < 192) {
        const int idx = (blk - 128) * 256 + t;         // 0..16383
        const int col = idx >> 7, k = idx & 127;
        Wencb[idx] = (k < IN_DIM) ? bfb(W_enc[(size_t)k * HID + col]) : (short)0;
    } else if (blk < 192 + BN_TOT / 4) {
        const int row = (blk - 192) * 4 + (t >> 6);    // b*116+i
        const int l = t & 63;
        const float v1 = adj[(size_t)row * N_NODES + l];
        const float v2 = (l < N_NODES - 64) ? adj[(size_t)row * N_NODES + 64 + l] : 0.f;
        const unsigned long long m1 = __ballot(v1 != 0.f);
        const unsigned long long m2 = __ballot(v2 != 0.f);
        if (l == 0) {
            uint4 v;
            v.x = (unsigned int)m1; v.y = (unsigned int)(m1 >> 32);
            v.z = (unsigned int)m2; v.w = (unsigned int)(m2 >> 32);
            *reinterpret_cast<uint4*>(&adjp[(size_t)row * 4]) = v;
        }
    } else {
        // xprep: 16 threads per row, short8 writes
        const int i = (blk - (192 + BN_TOT / 4)) * 256 + t;
        const int row = i >> 4, kb = (i & 15) * 8;
        short8 v;
#pragma unroll
        for (int e = 0; e < 8; ++e) {
            const int k = kb + e;
            v[e] = (k < IN_DIM) ? bfb(x[(size_t)row * IN_DIM + k]) : (short)0;
        }
        *reinterpret_cast<short8*>(&xb[(size_t)row * 128 + kb]) = v;
    }
}

// ---------------- classifier weight prep: wc1t bf16 [n][k] ----------------
__global__ __launch_bounds__(256) void wc1prep_kernel(
    const float* __restrict__ Wc1, short* __restrict__ wc1t)
{
    const int idx = blockIdx.x * 256 + threadIdx.x;  // n fastest
    const int k = idx >> 8, n = idx & 255;
    wc1t[(size_t)n * FLAT_DIM + k] = bfb(Wc1[(size_t)k * 256 + n]);
}

// ---------------- encoder via MFMA: hb0 = bf16(BN(elu(xb @ Wencb + b))) ---
__global__ __launch_bounds__(256) void enc_mfma(
    const short* __restrict__ xb, const short* __restrict__ Wencb,
    const float* __restrict__ bias,
    const float* __restrict__ g, const float* __restrict__ bta,
    const float* __restrict__ mn, const float* __restrict__ vr,
    short* __restrict__ houtb)
{
    const int t = threadIdx.x;
    const int lane = t & 63, w = t >> 6;
    const int half = lane >> 5, nn = lane & 31;
    const int row0 = blockIdx.x * 128 + w * 32;
    const short8* ap = reinterpret_cast<const short8*>(xb + (size_t)(row0 + nn) * 128);
    short8 af[8];
#pragma unroll
    for (int s = 0; s < 8; ++s) af[s] = ap[s * 2 + half];
#pragma unroll
    for (int ct = 0; ct < 4; ++ct) {
        const int col = ct * 32 + nn;
        const short8* bp = reinterpret_cast<const short8*>(Wencb + (size_t)col * 128);
        f32x16 acc = {};
#pragma unroll
        for (int s = 0; s < 8; ++s)
            acc = __builtin_amdgcn_mfma_f32_32x32x16_bf16(af[s], bp[s * 2 + half], acc, 0, 0, 0);
        const float bb = bias[col];
        const float gg = g[col], bbn = bta[col], mm = mn[col];
        const float rstd = rsqrtf(vr[col] + 1e-5f);
#pragma unroll
        for (int reg = 0; reg < 16; ++reg) {
            const int r = (reg & 3) + 8 * (reg >> 2) + 4 * half;
            float val = elu1(acc[reg] + bb);
            val = (val - mm) * rstd * gg + bbn;
            houtb[(size_t)(row0 + r) * HID + col] = bfb(val);
        }
    }
}

// ---------------- vn0 = vne + mean_n(h) (bf16 h) ----------------
__global__ __launch_bounds__(128) void vn0_kernel(
    const short* __restrict__ hb, const float* __restrict__ vne,
    float* __restrict__ vn)
{
    const int b = blockIdx.x, f = threadIdx.x;
    float s = 0.f;
    for (int n = 0; n < N_NODES; ++n)
        s += bf2f(hb[(size_t)(b * N_NODES + n) * HID + f]);
    vn[b * HID + f] = vne[f] + s * (1.f / N_NODES);
}

// ---------------- fused GAT layer (round-11 structure, bf16 h I/O) --------
// L=0: A=hb0, out=h1b (bf16).  L=1: A=h1b, corr trick for +0.1vn, out=hA f32.
template <int L>
__global__ __launch_bounds__(256, 4) void gat_fused(
    const short* __restrict__ hbin, short* __restrict__ houtb,
    float* __restrict__ houtf,
    const short* __restrict__ Wt, const short* __restrict__ Weij,
    const unsigned int* __restrict__ adjp,
    const float* __restrict__ g_, const float* __restrict__ bt_,
    const float* __restrict__ mn_, const float* __restrict__ vr_,
    const float* __restrict__ vn, const float* __restrict__ wcorr,
    const float* __restrict__ eicorr, float* __restrict__ premean)
{
    constexpr int KP = 136;
    constexpr int WP = 33;
    __shared__ __align__(16) __hip_bfloat16 s_p[N_NODES][KP];   // 31552 B
    __shared__ __align__(16) __hip_bfloat16 s_whsb[128][WP];    // 8448 B
    __shared__ float s_eir[232];                                // 40928 B total

    const int t = threadIdx.x;
    const int n_ = blockIdx.x;
    const int b = (n_ & 7) * 64 + (n_ >> 5);
    const int h = (n_ >> 3) & 3;

    const int lane = t & 63, w = t >> 6;
    const int half = lane >> 5, nn = lane & 31;
    const int row = w * 32 + nn;
    const int hr = (row < N_NODES) ? row : 0;

    // layer-2 correction terms (exact linearity: Wh(h+0.1v)=Wh·h + wcorr)
    float wc = 0.f, eic = 0.f, ejc = 0.f;
    if (L == 1) {
        wc = wcorr[(size_t)b * HID + h * 32 + nn];
        eic = eicorr[b * 8 + h * 2];
        ejc = eicorr[b * 8 + h * 2 + 1];
    }

    // ---- phase 1: Whs = h @ W-slice and [ei|ej] = h @ Weij, both MFMA ----
    {
        const short8* ap = reinterpret_cast<const short8*>(
            hbin + (size_t)(b * N_NODES + hr) * HID);
        const short8* wtp = reinterpret_cast<const short8*>(Wt + ((h * 32 + nn) << 7));
        const short8* wep = reinterpret_cast<const short8*>(Weij + ((h * 32 + nn) << 7));
        f32x16 wacc = {};
        f32x16 eacc = {};
#pragma unroll
        for (int s = 0; s < 8; ++s) {
            const int fi = s * 2 + half;
            const short8 af = ap[fi];
            wacc = __builtin_amdgcn_mfma_f32_32x32x16_bf16(af, wtp[fi], wacc, 0, 0, 0);
            eacc = __builtin_amdgcn_mfma_f32_32x32x16_bf16(af, wep[fi], eacc, 0, 0, 0);
        }
#pragma unroll
        for (int reg = 0; reg < 16; ++reg) {
            const int r = (reg & 3) + 8 * (reg >> 2) + 4 * half;
            s_whsb[w * 32 + r][nn] = __float2bfloat16(wacc[reg]);
        }
        if (nn == 0) {
#pragma unroll
            for (int reg = 0; reg < 16; ++reg) {
                const int r = w * 32 + (reg & 3) + 8 * (reg >> 2) + 4 * half;
                if (r < N_NODES) s_eir[r] = eacc[reg] + eic;
            }
        }
        if (nn == 1) {
#pragma unroll
            for (int reg = 0; reg < 16; ++reg) {
                const int r = w * 32 + (reg & 3) + 8 * (reg >> 2) + 4 * half;
                if (r < N_NODES) s_eir[N_NODES + r] = eacc[reg] + ejc;
            }
        }
    }
    __syncthreads();

    // ---- phase 2 (wave-local rows): unnormalized exp scores ----
    {
        const int l = lane;
        const float ejl = s_eir[N_NODES + l];
        const bool up = (l < N_NODES - 64);
        const float ejl2 = up ? s_eir[N_NODES + l + 64] : 0.f;
        const int i0 = w * 32;
        const int cnt = min(32, N_NODES - i0);   // 32,32,32,20
        const uint4* ap = reinterpret_cast<const uint4*>(
            adjp + ((size_t)b * N_NODES + i0) * 4);
        uint4 aw = ap[0];
        for (int ii = 0; ii < cnt; ++ii) {
            uint4 nw = aw;
            if (ii + 1 < cnt) nw = ap[ii + 1];
            const int i = i0 + ii;
            const float eii = s_eir[i];
            const unsigned int w1 = (l & 32) ? aw.y : aw.x;
            const unsigned int w2 = (l & 32) ? aw.w : aw.z;
            const bool bit1 = (w1 >> (l & 31)) & 1;
            const bool bit2 = (w2 >> (l & 31)) & 1;
            float e1 = eii + ejl;
            e1 = e1 > 0.f ? e1 : 0.2f * e1;
            const float x1 = bit1 ? __expf(e1) : 0.f;
            float x2 = 0.f;
            if (up) {
                float e2 = eii + ejl2;
                e2 = e2 > 0.f ? e2 : 0.2f * e2;
                x2 = bit2 ? __expf(e2) : 0.f;
            }
            s_p[i][l] = __float2bfloat16(x1);
            s_p[i][l + 64] = __float2bfloat16(x2);
            aw = nw;
        }
    }
    // no barrier: phase 3 reads only this wave's s_p rows

    // ---- phase 3: MFMA — O = P_u @ Whs and rowsum = P_u @ ones ----
    float psum = 0.f;
    {
        f32x16 acc = {};
        f32x16 accs = {};
        short8 ones;
#pragma unroll
        for (int e = 0; e < 8; ++e) ones[e] = (short)0x3F80;
#pragma unroll
        for (int s = 0; s < 8; ++s) {
            const int k0 = s * 16 + half * 8;
            const short8 afrag = *reinterpret_cast<const short8*>(
                &s_p[0][0] + (size_t)row * KP + k0);
            short8 bfrag;
#pragma unroll
            for (int e = 0; e < 8; ++e)
                bfrag[e] = *reinterpret_cast<const short*>(&s_whsb[k0 + e][nn]);
            acc = __builtin_amdgcn_mfma_f32_32x32x16_bf16(afrag, bfrag, acc, 0, 0, 0);
            accs = __builtin_amdgcn_mfma_f32_32x32x16_bf16(afrag, ones, accs, 0, 0, 0);
        }
        const int f = h * 32 + nn;
        const float G = g_[f], B = bt_[f], M = mn_[f];
        const float R = rsqrtf(vr_[f] + 1e-5f);
        const float vadd = (L == 1) ? 0.1f * vn[(size_t)b * HID + f] : 0.f;
#pragma unroll
        for (int reg = 0; reg < 16; ++reg) {
            const int r = (reg & 3) + 8 * (reg >> 2) + 4 * half;
            const int i = w * 32 + r;
            if (i < N_NODES) {
                const size_t off = ((size_t)b * N_NODES + i) * HID + f;
                const float aval = acc[reg] / accs[reg] + wc;
                float xv = elu1((aval - M) * R * G + B);
                float outv = xv + bf2f(*reinterpret_cast<const short*>(&s_whsb[i][nn])) + wc;
                if (L == 1) {
                    outv += bf2f(hbin[off]) + vadd;
                    houtf[off] = outv;
                } else {
                    houtb[off] = bfb(outv);
                }
                psum += outv;
            }
        }
    }
    psum += __shfl_xor(psum, 32);
    __syncthreads();                       // all waves done reading s_eir
    if (half == 0) s_eir[w * 32 + nn] = psum;
    __syncthreads();
    if (t < 32) {
        const float s = s_eir[t] + s_eir[32 + t] + s_eir[64 + t] + s_eir[96 + t];
        premean[(size_t)b * HID + h * 32 + t] = s * (1.f / N_NODES);
    }
}

// ---------------- vn MLP (+ optional corr emission for layer 2) -----------
template <bool EMIT>
__global__ __launch_bounds__(128) void vn_mlp_kernel(
    const float* __restrict__ prev, const float* __restrict__ premean,
    const float* __restrict__ Wv, const float* __restrict__ bv,
    const float* __restrict__ W2, const float* __restrict__ a2,
    float* __restrict__ vout, float* __restrict__ wcorr,
    float* __restrict__ eicorr)
{
    __shared__ float cat[2 * HID];
    const int b = blockIdx.x, f = threadIdx.x;
    cat[f] = prev[b * HID + f];
    cat[HID + f] = premean[b * HID + f];
    __syncthreads();
    float acc = bv[f];
    for (int k = 0; k < 2 * HID; ++k) acc += cat[k] * Wv[k * HID + f];
    const float o = elu1(acc);
    vout[b * HID + f] = o;
    if (EMIT) {
        __syncthreads();
        cat[f] = o;                       // reuse as s_vnn
        __syncthreads();
        float wcf = 0.f;
#pragma unroll 4
        for (int k = 0; k < HID; ++k) wcf += cat[k] * W2[k * HID + f];
        wcf *= 0.1f;
        wcorr[(size_t)b * HID + f] = wcf;
        __syncthreads();
        cat[f] = wcf;                     // reuse as s_wcorr
        __syncthreads();
        if (f < 8) {
            const int h = f >> 1, sel = f & 1;
            float e = 0.f;
#pragma unroll 8
            for (int d = 0; d < 32; ++d)
                e += cat[h * 32 + d] * a2[h * 64 + sel * 32 + d];
            eicorr[b * 8 + f] = e;
        }
    }
}

// ---------------- pooling + net attention + flat + LayerNorm --------------
__global__ __launch_bounds__(128) void pool_flat_kernel(
    const float* __restrict__ h, const float* __restrict__ vnf,
    const float* __restrict__ pm,
    const float* __restrict__ Wa1, const float* __restrict__ ba1,
    const float* __restrict__ Wa2, const float* __restrict__ ba2,
    const float* __restrict__ ln_g, const float* __restrict__ ln_b,
    float* __restrict__ out, short* __restrict__ flatb)
{
    __shared__ float s_pm[N_NODES * 9];
    __shared__ float s_p[9][HID];
    __shared__ float s_s[9];
    __shared__ float s_red[4];
    const int b = blockIdx.x, f = threadIdx.x;
    for (int idx = f; idx < N_NODES * 9; idx += 128) s_pm[idx] = pm[idx];
    float p[9] = {};
    __syncthreads();
    for (int n = 0; n < N_NODES; ++n) {
        const float hv = h[(size_t)b * HROW + n * HID + f];
#pragma unroll
        for (int k = 0; k < 9; ++k) p[k] += s_pm[n * 9 + k] * hv;
    }
#pragma unroll
    for (int k = 0; k < 9; ++k) s_p[k][f] = p[k];
    __syncthreads();
    for (int pass = 0; pass < 3; ++pass) {
        const int k = pass * 4 + (f >> 5);
        if (k < 9) {
            const int j = f & 31;
            float z = ba1[j];
            for (int d = 0; d < HID; ++d) z += s_p[k][d] * Wa1[d * 32 + j];
            z = tanhf(z);
            float part = z * Wa2[j];
#pragma unroll
            for (int off = 16; off; off >>= 1) part += __shfl_xor(part, off);
            if (j == 0) s_s[k] = part + ba2[0];
        }
    }
    __syncthreads();
    float smax = -1e30f;
#pragma unroll
    for (int k = 0; k < 9; ++k) smax = fmaxf(smax, s_s[k]);
    float wgt[9], ssum = 0.f;
#pragma unroll
    for (int k = 0; k < 9; ++k) { wgt[k] = expf(s_s[k] - smax); ssum += wgt[k]; }
    const float sinv = 1.f / ssum;
    float vals[10];
#pragma unroll
    for (int k = 0; k < 9; ++k) vals[k] = p[k] * wgt[k] * sinv;
    vals[9] = vnf[b * HID + f];
    float lsum = 0.f, lsq = 0.f;
#pragma unroll
    for (int q = 0; q < 10; ++q) { lsum += vals[q]; lsq += vals[q] * vals[q]; }
#pragma unroll
    for (int off = 32; off; off >>= 1) {
        lsum += __shfl_xor(lsum, off);
        lsq += __shfl_xor(lsq, off);
    }
    const int lane = f & 63, wid = f >> 6;
    if (lane == 0) { s_red[wid * 2] = lsum; s_red[wid * 2 + 1] = lsq; }
    __syncthreads();
    const float tot = s_red[0] + s_red[2];
    const float totsq = s_red[1] + s_red[3];
    const float mean = tot * (1.f / FLAT_DIM);
    const float var = totsq * (1.f / FLAT_DIM) - mean * mean;
    const float rstd = rsqrtf(var + 1e-5f);
    float* fout = out + 1024 + (size_t)b * FLAT_DIM;
    short* fb = flatb + (size_t)b * FLAT_DIM;
#pragma unroll
    for (int k = 0; k < 9; ++k) {
        const int j = k * HID + f;
        const float v = (vals[k] - mean) * rstd * ln_g[j] + ln_b[j];
        fout[j] = v;
        fb[j] = bfb(v);
    }
    const int j = 9 * HID + f;
    const float v9 = (vals[9] - mean) * rstd * ln_g[j] + ln_b[j];
    fout[j] = v9;
    fb[j] = bfb(v9);
}

// ---------------- classifier stage 1: hid = elu(flat @ Wc1 + bc1), MFMA ---
__global__ __launch_bounds__(256) void cls_mm_kernel(
    const short* __restrict__ flatb, const short* __restrict__ wc1t,
    const float* __restrict__ bc1, float* __restrict__ hid)
{
    const int t = threadIdx.x;
    const int lane = t & 63, w = t >> 6;
    const int half = lane >> 5, nn = lane & 31;
    const int mt = blockIdx.x >> 1;
    const int nh = blockIdx.x & 1;
    const int r0 = mt * 32;
    const int c0 = nh * 128 + w * 32;
    const short8* ap = reinterpret_cast<const short8*>(flatb + (size_t)(r0 + nn) * FLAT_DIM);
    const short8* bp = reinterpret_cast<const short8*>(wc1t + (size_t)(c0 + nn) * FLAT_DIM);
    f32x16 acc = {};
#pragma unroll 8
    for (int s = 0; s < 80; ++s) {
        const int fi = s * 2 + half;
        acc = __builtin_amdgcn_mfma_f32_32x32x16_bf16(ap[fi], bp[fi], acc, 0, 0, 0);
    }
    const float bb = bc1[c0 + nn];
#pragma unroll
    for (int reg = 0; reg < 16; ++reg) {
        const int row = (reg & 3) + 8 * (reg >> 2) + 4 * half;
        hid[(size_t)(r0 + row) * 256 + c0 + nn] = elu1(acc[reg] + bb);
    }
}

// ---------------- classifier stage 2: logits = hid @ Wc2 + bc2 (f32) ------
__global__ __launch_bounds__(256) void logits_kernel(
    const float* __restrict__ hid, const float* __restrict__ Wc2,
    const float* __restrict__ bc2, float* __restrict__ out)
{
    const int idx = blockIdx.x * 256 + threadIdx.x;  // 0..1023
    const int row = idx >> 1, c = idx & 1;
    const float4* hp = reinterpret_cast<const float4*>(hid + (size_t)row * 256);
    float acc = 0.f;
#pragma unroll 8
    for (int q = 0; q < 64; ++q) {
        const float4 hv = hp[q];
        acc += hv.x * Wc2[(q * 4 + 0) * 2 + c] + hv.y * Wc2[(q * 4 + 1) * 2 + c]
             + hv.z * Wc2[(q * 4 + 2) * 2 + c] + hv.w * Wc2[(q * 4 + 3) * 2 + c];
    }
    out[idx] = acc + bc2[c];
}

extern "C" void kernel_launch(void* const* d_in, const int* in_sizes, int n_in,
                              void* d_out, int out_size, void* d_ws, size_t ws_size,
                              hipStream_t stream)
{
    const float* x     = (const float*)d_in[0];
    const float* adj   = (const float*)d_in[1];
    const float* W_enc = (const float*)d_in[2];
    const float* b_enc = (const float*)d_in[3];
    const float* bn_g  = (const float*)d_in[4];
    const float* bn_b  = (const float*)d_in[5];
    const float* bn_m  = (const float*)d_in[6];
    const float* bn_v  = (const float*)d_in[7];
    const float* vne   = (const float*)d_in[8];
    const float* W1    = (const float*)d_in[9];
    const float* a1    = (const float*)d_in[10];
    const float* g1    = (const float*)d_in[11];
    const float* bt1   = (const float*)d_in[12];
    const float* m1    = (const float*)d_in[13];
    const float* v1    = (const float*)d_in[14];
    const float* W2    = (const float*)d_in[15];
    const float* a2    = (const float*)d_in[16];
    const float* g2    = (const float*)d_in[17];
    const float* bt2   = (const float*)d_in[18];
    const float* m2    = (const float*)d_in[19];
    const float* v2    = (const float*)d_in[20];
    const float* Wv    = (const float*)d_in[21];
    const float* bv    = (const float*)d_in[22];
    const float* pm    = (const float*)d_in[23];
    const float* Wa1   = (const float*)d_in[24];
    const float* ba1   = (const float*)d_in[25];
    const float* Wa2   = (const float*)d_in[26];
    const float* ba2   = (const float*)d_in[27];
    const float* ln_g  = (const float*)d_in[28];
    const float* ln_b  = (const float*)d_in[29];
    const float* Wc1   = (const float*)d_in[30];
    const float* bc1   = (const float*)d_in[31];
    const float* Wc2   = (const float*)d_in[32];
    const float* bc2   = (const float*)d_in[33];
    float* out = (float*)d_out;

    float* ws = (float*)d_ws;
    float* hA   = ws;                                  // 7,602,176 floats (final h)
    short* hb0  = (short*)(hA + (size_t)BN_TOT * HID); // 7,602,176 shorts (enc out)
    short* h1b  = hb0 + (size_t)BN_TOT * HID;          // 7,602,176 shorts (gat1 out)
    float* tail = (float*)(h1b + (size_t)BN_TOT * HID);
    float* vn0g = tail;
    float* vnn  = vn0g + BATCH * HID;
    float* vnf  = vnn + BATCH * HID;
    float* pms1 = vnf + BATCH * HID;
    float* pms2 = pms1 + BATCH * HID;
    float* wcorr = pms2 + BATCH * HID;                 // 65,536 floats
    float* eicorr = wcorr + BATCH * HID;               // 4,096 floats
    unsigned int* adjp = (unsigned int*)(eicorr + BATCH * 8);  // 237,568 uints
    short* Wt1  = (short*)(adjp + (size_t)BN_TOT * 4);
    short* We1  = Wt1 + 16384;
    short* Wt2  = We1 + 16384;
    short* We2  = Wt2 + 16384;
    short* Wencb = We2 + 16384;
    // transient aliases:
    short* xb    = h1b;                   // enc input; overwritten by gat1 output
    short* flatb = hb0;                   // classifier scratch (hb0 dead after gat1)
    short* wc1t  = h1b;                   // h1b dead after gat2
    float* hid   = (float*)(wc1t + 256 * FLAT_DIM);

    // merged prep (Wt/Weij, Wencb, adjpack, xprep)
    const int prep_blocks = 192 + BN_TOT / 4 + (BN_TOT * 16) / 256;
    prep_all<<<prep_blocks, 256, 0, stream>>>(x, adj, W_enc, W1, a1, W2, a2,
                                              xb, adjp, Wencb, Wt1, We1, Wt2, We2);
    // encoder: xb(=h1b) -> hb0 (bf16)
    enc_mfma<<<BN_TOT / 128, 256, 0, stream>>>(xb, Wencb, b_enc, bn_g, bn_b,
                                               bn_m, bn_v, hb0);
    vn0_kernel<<<BATCH, 128, 0, stream>>>(hb0, vne, vn0g);
    // GAT layer 1: hb0 -> h1b (bf16)
    gat_fused<0><<<BATCH * HEADS, 256, 0, stream>>>(
        hb0, h1b, nullptr, Wt1, We1, adjp, g1, bt1, m1, v1,
        nullptr, nullptr, nullptr, pms1);
    // vn MLP + layer-2 correction terms (wcorr = 0.1*vnn@W2, eicorr)
    vn_mlp_kernel<true><<<BATCH, 128, 0, stream>>>(vn0g, pms1, Wv, bv, W2, a2,
                                                   vnn, wcorr, eicorr);
    // GAT layer 2: h1b -> hA (f32), corr trick handles +0.1*vnn
    gat_fused<1><<<BATCH * HEADS, 256, 0, stream>>>(
        h1b, nullptr, hA, Wt2, We2, adjp, g2, bt2, m2, v2,
        vnn, wcorr, eicorr, pms2);
    vn_mlp_kernel<false><<<BATCH, 128, 0, stream>>>(vnn, pms2, Wv, bv, nullptr,
                                                    nullptr, vnf, nullptr, nullptr);
    // classifier weight prep into h1b (dead after gat2)
    wc1prep_kernel<<<1280, 256, 0, stream>>>(Wc1, wc1t);
    // pooling + flat + LayerNorm (writes out[1024:] and flatb)
    pool_flat_kernel<<<BATCH, 128, 0, stream>>>(hA, vnf, pm, Wa1, ba1, Wa2, ba2,
                                                ln_g, ln_b, out, flatb);
    // classifier: MFMA GEMM + tiny logits pass (writes out[0:1024])
    cls_mm_kernel<<<32, 256, 0, stream>>>(flatb, wc1t, bc1, hid);
    logits_kernel<<<4, 256, 0, stream>>>(hid, Wc2, bc2, out);
}

// Round 14
// 211.041 us; speedup vs baseline: 1.1600x; 1.0386x over previous
//
#include <hip/hip_runtime.h>
#include <hip/hip_bf16.h>
#include <math.h>

#define BATCH 512
#define N_NODES 116
#define IN_DIM 123
#define HID 128
#define HEADS 4
#define FLAT_DIM 1280

static constexpr int BN_TOT = BATCH * N_NODES;      // 59392
static constexpr int HROW = N_NODES * HID;          // 14848

typedef short short8 __attribute__((ext_vector_type(8)));
typedef float f32x16 __attribute__((ext_vector_type(16)));

__device__ __forceinline__ float elu1(float x) {
    return x > 0.f ? x : __expf(x) - 1.f;
}
__device__ __forceinline__ short bfb(float x) {
    __hip_bfloat16 b = __float2bfloat16(x);
    return *reinterpret_cast<short*>(&b);
}
__device__ __forceinline__ float bf2f(short s) {
    return __bfloat162float(*reinterpret_cast<__hip_bfloat16*>(&s));
}

// ---------------- merged prep: Wt/Weij x2, Wencb, adjpack, xprep ----------
__global__ __launch_bounds__(256) void prep_all(
    const float* __restrict__ x, const float* __restrict__ adj,
    const float* __restrict__ W_enc,
    const float* __restrict__ W1, const float* __restrict__ a1,
    const float* __restrict__ W2, const float* __restrict__ a2,
    short* __restrict__ xb, unsigned int* __restrict__ adjp,
    short* __restrict__ Wencb,
    short* __restrict__ Wt1, short* __restrict__ We1,
    short* __restrict__ Wt2, short* __restrict__ We2)
{
    const int blk = blockIdx.x, t = threadIdx.x;
    if (blk < 128) {
        const float* W = (blk < 64) ? W1 : W2;
        const float* a = (blk < 64) ? a1 : a2;
        short* Wt = (blk < 64) ? Wt1 : Wt2;
        short* We = (blk < 64) ? We1 : We2;
        const int idx = (blk & 63) * 256 + t;          // 0..16383
        const int h = idx >> 12, nn = (idx >> 7) & 31, k = idx & 127;
        Wt[idx] = bfb(W[k * HID + h * 32 + nn]);
        short wv = 0;
        if (nn < 2) {
            const float* ap = a + h * 64 + nn * 32;
            float s = 0.f;
#pragma unroll 8
            for (int d = 0; d < 32; ++d) s += W[k * HID + h * 32 + d] * ap[d];
            wv = bfb(s);
        }
        We[idx] = wv;
    } else if (blk < 192) {
        const int idx = (blk - 128) * 256 + t;         // 0..16383
        const int col = idx >> 7, k = idx & 127;
        Wencb[idx] = (k < IN_DIM) ? bfb(W_enc[(size_t)k * HID + col]) : (short)0;
    } else if (blk < 192 + BN_TOT / 4) {
        const int row = (blk - 192) * 4 + (t >> 6);    // b*116+i
        const int l = t & 63;
        const float v1 = adj[(size_t)row * N_NODES + l];
        const float v2 = (l < N_NODES - 64) ? adj[(size_t)row * N_NODES + 64 + l] : 0.f;
        const unsigned long long m1 = __ballot(v1 != 0.f);
        const unsigned long long m2 = __ballot(v2 != 0.f);
        if (l == 0) {
            uint4 v;
            v.x = (unsigned int)m1; v.y = (unsigned int)(m1 >> 32);
            v.z = (unsigned int)m2; v.w = (unsigned int)(m2 >> 32);
            *reinterpret_cast<uint4*>(&adjp[(size_t)row * 4]) = v;
        }
    } else {
        // xprep: 16 threads per row, short8 writes
        const int i = (blk - (192 + BN_TOT / 4)) * 256 + t;
        const int row = i >> 4, kb = (i & 15) * 8;
        short8 v;
#pragma unroll
        for (int e = 0; e < 8; ++e) {
            const int k = kb + e;
            v[e] = (k < IN_DIM) ? bfb(x[(size_t)row * IN_DIM + k]) : (short)0;
        }
        *reinterpret_cast<short8*>(&xb[(size_t)row * 128 + kb]) = v;
    }
}

// ---------------- classifier weight prep: wc1t bf16 [n][k] ----------------
__global__ __launch_bounds__(256) void wc1prep_kernel(
    const float* __restrict__ Wc1, short* __restrict__ wc1t)
{
    const int idx = blockIdx.x * 256 + threadIdx.x;  // n fastest
    const int k = idx >> 8, n = idx & 255;
    wc1t[(size_t)n * FLAT_DIM + k] = bfb(Wc1[(size_t)k * 256 + n]);
}

// ---------------- encoder via MFMA: hb0 = bf16(BN(elu(xb @ Wencb + b))) ---
__global__ __launch_bounds__(256) void enc_mfma(
    const short* __restrict__ xb, const short* __restrict__ Wencb,
    const float* __restrict__ bias,
    const float* __restrict__ g, const float* __restrict__ bta,
    const float* __restrict__ mn, const float* __restrict__ vr,
    short* __restrict__ houtb)
{
    const int t = threadIdx.x;
    const int lane = t & 63, w = t >> 6;
    const int half = lane >> 5, nn = lane & 31;
    const int row0 = blockIdx.x * 128 + w * 32;
    const short8* ap = reinterpret_cast<const short8*>(xb + (size_t)(row0 + nn) * 128);
    short8 af[8];
#pragma unroll
    for (int s = 0; s < 8; ++s) af[s] = ap[s * 2 + half];
#pragma unroll
    for (int ct = 0; ct < 4; ++ct) {
        const int col = ct * 32 + nn;
        const short8* bp = reinterpret_cast<const short8*>(Wencb + (size_t)col * 128);
        f32x16 acc = {};
#pragma unroll
        for (int s = 0; s < 8; ++s)
            acc = __builtin_amdgcn_mfma_f32_32x32x16_bf16(af[s], bp[s * 2 + half], acc, 0, 0, 0);
        const float bb = bias[col];
        const float gg = g[col], bbn = bta[col], mm = mn[col];
        const float rstd = rsqrtf(vr[col] + 1e-5f);
#pragma unroll
        for (int reg = 0; reg < 16; ++reg) {
            const int r = (reg & 3) + 8 * (reg >> 2) + 4 * half;
            float val = elu1(acc[reg] + bb);
            val = (val - mm) * rstd * gg + bbn;
            houtb[(size_t)(row0 + r) * HID + col] = bfb(val);
        }
    }
}

// ---------------- vn0 = vne + mean_n(h) (bf16 h) ----------------
__global__ __launch_bounds__(128) void vn0_kernel(
    const short* __restrict__ hb, const float* __restrict__ vne,
    float* __restrict__ vn)
{
    const int b = blockIdx.x, f = threadIdx.x;
    float s = 0.f;
    for (int n = 0; n < N_NODES; ++n)
        s += bf2f(hb[(size_t)(b * N_NODES + n) * HID + f]);
    vn[b * HID + f] = vne[f] + s * (1.f / N_NODES);
}

// ---------------- fused GAT layer (bf16 h in AND out) ---------------------
// L=0: A=hb0 -> h1b.  L=1: A=h1b, corr trick for +0.1vn, -> hb0 (final h).
template <int L>
__global__ __launch_bounds__(256, 4) void gat_fused(
    const short* __restrict__ hbin, short* __restrict__ houtb,
    const short* __restrict__ Wt, const short* __restrict__ Weij,
    const unsigned int* __restrict__ adjp,
    const float* __restrict__ g_, const float* __restrict__ bt_,
    const float* __restrict__ mn_, const float* __restrict__ vr_,
    const float* __restrict__ vn, const float* __restrict__ wcorr,
    const float* __restrict__ eicorr, float* __restrict__ premean)
{
    constexpr int KP = 136;
    constexpr int WP = 33;
    __shared__ __align__(16) __hip_bfloat16 s_p[N_NODES][KP];   // 31552 B
    __shared__ __align__(16) __hip_bfloat16 s_whsb[128][WP];    // 8448 B
    __shared__ float s_eir[232];                                // 40928 B total

    const int t = threadIdx.x;
    const int n_ = blockIdx.x;
    const int b = (n_ & 7) * 64 + (n_ >> 5);
    const int h = (n_ >> 3) & 3;

    const int lane = t & 63, w = t >> 6;
    const int half = lane >> 5, nn = lane & 31;
    const int row = w * 32 + nn;
    const int hr = (row < N_NODES) ? row : 0;

    // layer-2 correction terms (exact linearity: Wh(h+0.1v)=Wh·h + wcorr)
    float wc = 0.f, eic = 0.f, ejc = 0.f;
    if (L == 1) {
        wc = wcorr[(size_t)b * HID + h * 32 + nn];
        eic = eicorr[b * 8 + h * 2];
        ejc = eicorr[b * 8 + h * 2 + 1];
    }

    // ---- phase 1: Whs = h @ W-slice and [ei|ej] = h @ Weij, both MFMA ----
    {
        const short8* ap = reinterpret_cast<const short8*>(
            hbin + (size_t)(b * N_NODES + hr) * HID);
        const short8* wtp = reinterpret_cast<const short8*>(Wt + ((h * 32 + nn) << 7));
        const short8* wep = reinterpret_cast<const short8*>(Weij + ((h * 32 + nn) << 7));
        f32x16 wacc = {};
        f32x16 eacc = {};
#pragma unroll
        for (int s = 0; s < 8; ++s) {
            const int fi = s * 2 + half;
            const short8 af = ap[fi];
            wacc = __builtin_amdgcn_mfma_f32_32x32x16_bf16(af, wtp[fi], wacc, 0, 0, 0);
            eacc = __builtin_amdgcn_mfma_f32_32x32x16_bf16(af, wep[fi], eacc, 0, 0, 0);
        }
#pragma unroll
        for (int reg = 0; reg < 16; ++reg) {
            const int r = (reg & 3) + 8 * (reg >> 2) + 4 * half;
            s_whsb[w * 32 + r][nn] = __float2bfloat16(wacc[reg]);
        }
        if (nn == 0) {
#pragma unroll
            for (int reg = 0; reg < 16; ++reg) {
                const int r = w * 32 + (reg & 3) + 8 * (reg >> 2) + 4 * half;
                if (r < N_NODES) s_eir[r] = eacc[reg] + eic;
            }
        }
        if (nn == 1) {
#pragma unroll
            for (int reg = 0; reg < 16; ++reg) {
                const int r = w * 32 + (reg & 3) + 8 * (reg >> 2) + 4 * half;
                if (r < N_NODES) s_eir[N_NODES + r] = eacc[reg] + ejc;
            }
        }
    }
    __syncthreads();

    // ---- phase 2 (wave-local rows): unnormalized exp scores, unrolled ----
    {
        const int l = lane;
        const float ejl = s_eir[N_NODES + l];
        const bool up = (l < N_NODES - 64);
        const float ejl2 = up ? s_eir[N_NODES + l + 64] : 0.f;
        const int i0 = w * 32;
        const uint4* ap = reinterpret_cast<const uint4*>(
            adjp + ((size_t)b * N_NODES + i0) * 4);
        auto body = [&](int ii) {
            const int i = i0 + ii;
            const uint4 aw = ap[ii];
            const float eii = s_eir[i];
            const unsigned int w1 = (l & 32) ? aw.y : aw.x;
            const unsigned int w2 = (l & 32) ? aw.w : aw.z;
            const bool bit1 = (w1 >> (l & 31)) & 1;
            const bool bit2 = (w2 >> (l & 31)) & 1;
            float e1 = eii + ejl;
            e1 = e1 > 0.f ? e1 : 0.2f * e1;
            const float x1 = bit1 ? __expf(e1) : 0.f;
            float x2 = 0.f;
            if (up) {
                float e2 = eii + ejl2;
                e2 = e2 > 0.f ? e2 : 0.2f * e2;
                x2 = bit2 ? __expf(e2) : 0.f;
            }
            s_p[i][l] = __float2bfloat16(x1);
            s_p[i][l + 64] = __float2bfloat16(x2);
        };
        if (w < 3) {
#pragma unroll 8
            for (int ii = 0; ii < 32; ++ii) body(ii);
        } else {
#pragma unroll 5
            for (int ii = 0; ii < 20; ++ii) body(ii);
        }
    }
    // no barrier: phase 3 reads only this wave's s_p rows

    // ---- phase 3: MFMA — O = P_u @ Whs and rowsum = P_u @ ones ----
    float psum = 0.f;
    {
        f32x16 acc = {};
        f32x16 accs = {};
        short8 ones;
#pragma unroll
        for (int e = 0; e < 8; ++e) ones[e] = (short)0x3F80;
#pragma unroll
        for (int s = 0; s < 8; ++s) {
            const int k0 = s * 16 + half * 8;
            const short8 afrag = *reinterpret_cast<const short8*>(
                &s_p[0][0] + (size_t)row * KP + k0);
            short8 bfrag;
#pragma unroll
            for (int e = 0; e < 8; ++e)
                bfrag[e] = *reinterpret_cast<const short*>(&s_whsb[k0 + e][nn]);
            acc = __builtin_amdgcn_mfma_f32_32x32x16_bf16(afrag, bfrag, acc, 0, 0, 0);
            accs = __builtin_amdgcn_mfma_f32_32x32x16_bf16(afrag, ones, accs, 0, 0, 0);
        }
        const int f = h * 32 + nn;
        const float G = g_[f], B = bt_[f], M = mn_[f];
        const float R = rsqrtf(vr_[f] + 1e-5f);
        const float vadd = (L == 1) ? 0.1f * vn[(size_t)b * HID + f] : 0.f;
#pragma unroll
        for (int reg = 0; reg < 16; ++reg) {
            const int r = (reg & 3) + 8 * (reg >> 2) + 4 * half;
            const int i = w * 32 + r;
            if (i < N_NODES) {
                const size_t off = ((size_t)b * N_NODES + i) * HID + f;
                const float aval = acc[reg] / accs[reg] + wc;
                float xv = elu1((aval - M) * R * G + B);
                float outv = xv + bf2f(*reinterpret_cast<const short*>(&s_whsb[i][nn])) + wc;
                if (L == 1) outv += bf2f(hbin[off]) + vadd;
                houtb[off] = bfb(outv);
                psum += outv;
            }
        }
    }
    psum += __shfl_xor(psum, 32);
    __syncthreads();                       // all waves done reading s_eir
    if (half == 0) s_eir[w * 32 + nn] = psum;
    __syncthreads();
    if (t < 32) {
        const float s = s_eir[t] + s_eir[32 + t] + s_eir[64 + t] + s_eir[96 + t];
        premean[(size_t)b * HID + h * 32 + t] = s * (1.f / N_NODES);
    }
}

// ---------------- vn MLP (+ corr emission for layer 2) --------------------
__global__ __launch_bounds__(128) void vn_mlp_kernel(
    const float* __restrict__ prev, const float* __restrict__ premean,
    const float* __restrict__ Wv, const float* __restrict__ bv,
    const float* __restrict__ W2, const float* __restrict__ a2,
    float* __restrict__ vout, float* __restrict__ wcorr,
    float* __restrict__ eicorr)
{
    __shared__ float cat[2 * HID];
    const int b = blockIdx.x, f = threadIdx.x;
    cat[f] = prev[b * HID + f];
    cat[HID + f] = premean[b * HID + f];
    __syncthreads();
    float acc = bv[f];
    for (int k = 0; k < 2 * HID; ++k) acc += cat[k] * Wv[k * HID + f];
    const float o = elu1(acc);
    vout[b * HID + f] = o;
    __syncthreads();
    cat[f] = o;                       // reuse as s_vnn
    __syncthreads();
    float wcf = 0.f;
#pragma unroll 4
    for (int k = 0; k < HID; ++k) wcf += cat[k] * W2[k * HID + f];
    wcf *= 0.1f;
    wcorr[(size_t)b * HID + f] = wcf;
    __syncthreads();
    cat[f] = wcf;                     // reuse as s_wcorr
    __syncthreads();
    if (f < 8) {
        const int h = f >> 1, sel = f & 1;
        float e = 0.f;
#pragma unroll 8
        for (int d = 0; d < 32; ++d)
            e += cat[h * 32 + d] * a2[h * 64 + sel * 32 + d];
        eicorr[b * 8 + f] = e;
    }
}

// ---------------- pooling + vnf MLP + net attention + flat + LayerNorm ----
__global__ __launch_bounds__(128) void pool_flat_kernel(
    const short* __restrict__ hb, const float* __restrict__ vnn,
    const float* __restrict__ pms2,
    const float* __restrict__ Wv, const float* __restrict__ bv,
    const float* __restrict__ pm,
    const float* __restrict__ Wa1, const float* __restrict__ ba1,
    const float* __restrict__ Wa2, const float* __restrict__ ba2,
    const float* __restrict__ ln_g, const float* __restrict__ ln_b,
    float* __restrict__ out, short* __restrict__ flatb)
{
    __shared__ float s_pm[N_NODES * 9];
    __shared__ float s_v[2 * HID];
    __shared__ float s_p[9][HID];
    __shared__ float s_s[9];
    __shared__ float s_red[4];
    const int b = blockIdx.x, f = threadIdx.x;
    for (int idx = f; idx < N_NODES * 9; idx += 128) s_pm[idx] = pm[idx];
    s_v[f] = vnn[b * HID + f];
    s_v[HID + f] = pms2[b * HID + f];
    __syncthreads();
    // vnf = elu(cat([vnn, pms2]) @ Wv + bv)  (fused final vn MLP)
    float vacc = bv[f];
    for (int k = 0; k < 2 * HID; ++k) vacc += s_v[k] * Wv[k * HID + f];
    const float vnf_f = elu1(vacc);
    // pooling over nodes (bf16 h)
    float p[9] = {};
    for (int n = 0; n < N_NODES; ++n) {
        const float hv = bf2f(hb[(size_t)b * HROW + n * HID + f]);
#pragma unroll
        for (int k = 0; k < 9; ++k) p[k] += s_pm[n * 9 + k] * hv;
    }
#pragma unroll
    for (int k = 0; k < 9; ++k) s_p[k][f] = p[k];
    __syncthreads();
    for (int pass = 0; pass < 3; ++pass) {
        const int k = pass * 4 + (f >> 5);
        if (k < 9) {
            const int j = f & 31;
            float z = ba1[j];
            for (int d = 0; d < HID; ++d) z += s_p[k][d] * Wa1[d * 32 + j];
            z = tanhf(z);
            float part = z * Wa2[j];
#pragma unroll
            for (int off = 16; off; off >>= 1) part += __shfl_xor(part, off);
            if (j == 0) s_s[k] = part + ba2[0];
        }
    }
    __syncthreads();
    float smax = -1e30f;
#pragma unroll
    for (int k = 0; k < 9; ++k) smax = fmaxf(smax, s_s[k]);
    float wgt[9], ssum = 0.f;
#pragma unroll
    for (int k = 0; k < 9; ++k) { wgt[k] = expf(s_s[k] - smax); ssum += wgt[k]; }
    const float sinv = 1.f / ssum;
    float vals[10];
#pragma unroll
    for (int k = 0; k < 9; ++k) vals[k] = p[k] * wgt[k] * sinv;
    vals[9] = vnf_f;
    float lsum = 0.f, lsq = 0.f;
#pragma unroll
    for (int q = 0; q < 10; ++q) { lsum += vals[q]; lsq += vals[q] * vals[q]; }
#pragma unroll
    for (int off = 32; off; off >>= 1) {
        lsum += __shfl_xor(lsum, off);
        lsq += __shfl_xor(lsq, off);
    }
    const int lane = f & 63, wid = f >> 6;
    if (lane == 0) { s_red[wid * 2] = lsum; s_red[wid * 2 + 1] = lsq; }
    __syncthreads();
    const float tot = s_red[0] + s_red[2];
    const float totsq = s_red[1] + s_red[3];
    const float mean = tot * (1.f / FLAT_DIM);
    const float var = totsq * (1.f / FLAT_DIM) - mean * mean;
    const float rstd = rsqrtf(var + 1e-5f);
    float* fout = out + 1024 + (size_t)b * FLAT_DIM;
    short* fb = flatb + (size_t)b * FLAT_DIM;
#pragma unroll
    for (int k = 0; k < 9; ++k) {
        const int j = k * HID + f;
        const float v = (vals[k] - mean) * rstd * ln_g[j] + ln_b[j];
        fout[j] = v;
        fb[j] = bfb(v);
    }
    const int j = 9 * HID + f;
    const float v9 = (vals[9] - mean) * rstd * ln_g[j] + ln_b[j];
    fout[j] = v9;
    fb[j] = bfb(v9);
}

// ---------------- classifier stage 1: one wave per 32x32 tile -------------
__global__ __launch_bounds__(64) void cls_mm_kernel(
    const short* __restrict__ flatb, const short* __restrict__ wc1t,
    const float* __restrict__ bc1, float* __restrict__ hid)
{
    const int lane = threadIdx.x;
    const int half = lane >> 5, nn = lane & 31;
    const int mt = blockIdx.x >> 3;          // 16 M-tiles
    const int ct = blockIdx.x & 7;           // 8 N-tiles
    const int r0 = mt * 32;
    const int c0 = ct * 32;
    const short8* ap = reinterpret_cast<const short8*>(flatb + (size_t)(r0 + nn) * FLAT_DIM);
    const short8* bp = reinterpret_cast<const short8*>(wc1t + (size_t)(c0 + nn) * FLAT_DIM);
    f32x16 acc = {};
#pragma unroll 8
    for (int s = 0; s < 80; ++s) {
        const int fi = s * 2 + half;
        acc = __builtin_amdgcn_mfma_f32_32x32x16_bf16(ap[fi], bp[fi], acc, 0, 0, 0);
    }
    const float bb = bc1[c0 + nn];
#pragma unroll
    for (int reg = 0; reg < 16; ++reg) {
        const int row = (reg & 3) + 8 * (reg >> 2) + 4 * half;
        hid[(size_t)(r0 + row) * 256 + c0 + nn] = elu1(acc[reg] + bb);
    }
}

// ---------------- classifier stage 2: logits = hid @ Wc2 + bc2 (f32) ------
__global__ __launch_bounds__(256) void logits_kernel(
    const float* __restrict__ hid, const float* __restrict__ Wc2,
    const float* __restrict__ bc2, float* __restrict__ out)
{
    const int idx = blockIdx.x * 256 + threadIdx.x;  // 0..1023
    const int row = idx >> 1, c = idx & 1;
    const float4* hp = reinterpret_cast<const float4*>(hid + (size_t)row * 256);
    float acc = 0.f;
#pragma unroll 8
    for (int q = 0; q < 64; ++q) {
        const float4 hv = hp[q];
        acc += hv.x * Wc2[(q * 4 + 0) * 2 + c] + hv.y * Wc2[(q * 4 + 1) * 2 + c]
             + hv.z * Wc2[(q * 4 + 2) * 2 + c] + hv.w * Wc2[(q * 4 + 3) * 2 + c];
    }
    out[idx] = acc + bc2[c];
}

extern "C" void kernel_launch(void* const* d_in, const int* in_sizes, int n_in,
                              void* d_out, int out_size, void* d_ws, size_t ws_size,
                              hipStream_t stream)
{
    const float* x     = (const float*)d_in[0];
    const float* adj   = (const float*)d_in[1];
    const float* W_enc = (const float*)d_in[2];
    const float* b_enc = (const float*)d_in[3];
    const float* bn_g  = (const float*)d_in[4];
    const float* bn_b  = (const float*)d_in[5];
    const float* bn_m  = (const float*)d_in[6];
    const float* bn_v  = (const float*)d_in[7];
    const float* vne   = (const float*)d_in[8];
    const float* W1    = (const float*)d_in[9];
    const float* a1    = (const float*)d_in[10];
    const float* g1    = (const float*)d_in[11];
    const float* bt1   = (const float*)d_in[12];
    const float* m1    = (const float*)d_in[13];
    const float* v1    = (const float*)d_in[14];
    const float* W2    = (const float*)d_in[15];
    const float* a2    = (const float*)d_in[16];
    const float* g2    = (const float*)d_in[17];
    const float* bt2   = (const float*)d_in[18];
    const float* m2    = (const float*)d_in[19];
    const float* v2    = (const float*)d_in[20];
    const float* Wv    = (const float*)d_in[21];
    const float* bv    = (const float*)d_in[22];
    const float* pm    = (const float*)d_in[23];
    const float* Wa1   = (const float*)d_in[24];
    const float* ba1   = (const float*)d_in[25];
    const float* Wa2   = (const float*)d_in[26];
    const float* ba2   = (const float*)d_in[27];
    const float* ln_g  = (const float*)d_in[28];
    const float* ln_b  = (const float*)d_in[29];
    const float* Wc1   = (const float*)d_in[30];
    const float* bc1   = (const float*)d_in[31];
    const float* Wc2   = (const float*)d_in[32];
    const float* bc2   = (const float*)d_in[33];
    float* out = (float*)d_out;

    // region1 (30.4 MB): xb (dead after enc) -> flatb + wc1t + hid
    char* ws = (char*)d_ws;
    short* xb    = (short*)ws;
    short* flatb = (short*)ws;
    short* wc1t  = flatb + (size_t)BATCH * FLAT_DIM;
    float* hid   = (float*)(wc1t + 256 * FLAT_DIM);
    short* hb0  = (short*)(ws + (size_t)BN_TOT * HID * 4);  // enc out, then final h
    short* h1b  = hb0 + (size_t)BN_TOT * HID;               // gat1 out
    float* tail = (float*)(h1b + (size_t)BN_TOT * HID);
    float* vn0g = tail;
    float* vnn  = vn0g + BATCH * HID;
    float* pms1 = vnn + BATCH * HID;
    float* pms2 = pms1 + BATCH * HID;
    float* wcorr = pms2 + BATCH * HID;
    float* eicorr = wcorr + BATCH * HID;
    unsigned int* adjp = (unsigned int*)(eicorr + BATCH * 8);
    short* Wt1  = (short*)(adjp + (size_t)BN_TOT * 4);
    short* We1  = Wt1 + 16384;
    short* Wt2  = We1 + 16384;
    short* We2  = Wt2 + 16384;
    short* Wencb = We2 + 16384;

    // merged prep (Wt/Weij, Wencb, adjpack, xprep)
    const int prep_blocks = 192 + BN_TOT / 4 + (BN_TOT * 16) / 256;
    prep_all<<<prep_blocks, 256, 0, stream>>>(x, adj, W_enc, W1, a1, W2, a2,
                                              xb, adjp, Wencb, Wt1, We1, Wt2, We2);
    // encoder: xb -> hb0 (bf16)
    enc_mfma<<<BN_TOT / 128, 256, 0, stream>>>(xb, Wencb, b_enc, bn_g, bn_b,
                                               bn_m, bn_v, hb0);
    vn0_kernel<<<BATCH, 128, 0, stream>>>(hb0, vne, vn0g);
    // GAT layer 1: hb0 -> h1b (bf16)
    gat_fused<0><<<BATCH * HEADS, 256, 0, stream>>>(
        hb0, h1b, Wt1, We1, adjp, g1, bt1, m1, v1,
        nullptr, nullptr, nullptr, pms1);
    // vn MLP + layer-2 correction terms
    vn_mlp_kernel<<<BATCH, 128, 0, stream>>>(vn0g, pms1, Wv, bv, W2, a2,
                                             vnn, wcorr, eicorr);
    // GAT layer 2: h1b -> hb0 (final h, bf16)
    gat_fused<1><<<BATCH * HEADS, 256, 0, stream>>>(
        h1b, hb0, Wt2, We2, adjp, g2, bt2, m2, v2,
        vnn, wcorr, eicorr, pms2);
    // classifier weight prep into region1 (xb dead)
    wc1prep_kernel<<<1280, 256, 0, stream>>>(Wc1, wc1t);
    // pooling + fused vnf + flat + LayerNorm (writes out[1024:] and flatb)
    pool_flat_kernel<<<BATCH, 128, 0, stream>>>(hb0, vnn, pms2, Wv, bv, pm,
                                                Wa1, ba1, Wa2, ba2,
                                                ln_g, ln_b, out, flatb);
    // classifier: MFMA GEMM (128 waves) + tiny logits pass
    cls_mm_kernel<<<128, 64, 0, stream>>>(flatb, wc1t, bc1, hid);
    logits_kernel<<<4, 256, 0, stream>>>(hid, Wc2, bc2, out);
}

// Round 15
// 193.380 us; speedup vs baseline: 1.2659x; 1.0913x over previous
//
#include <hip/hip_runtime.h>
#include <hip/hip_bf16.h>
#include <math.h>

#define BATCH 512
#define N_NODES 116
#define IN_DIM 123
#define HID 128
#define HEADS 4
#define FLAT_DIM 1280

static constexpr int BN_TOT = BATCH * N_NODES;      // 59392
static constexpr int HROW = N_NODES * HID;          // 14848

typedef short short8 __attribute__((ext_vector_type(8)));
typedef float f32x16 __attribute__((ext_vector_type(16)));

__device__ __forceinline__ float elu1(float x) {
    return x > 0.f ? x : __expf(x) - 1.f;
}
__device__ __forceinline__ short bfb(float x) {
    __hip_bfloat16 b = __float2bfloat16(x);
    return *reinterpret_cast<short*>(&b);
}
__device__ __forceinline__ float bf2f(short s) {
    return __bfloat162float(*reinterpret_cast<__hip_bfloat16*>(&s));
}

// ------- merged prep: Wt/Weij x2, Wencb, adjpack, xprep, wc1prep ----------
__global__ __launch_bounds__(256) void prep_all(
    const float* __restrict__ x, const float* __restrict__ adj,
    const float* __restrict__ W_enc, const float* __restrict__ Wc1,
    const float* __restrict__ W1, const float* __restrict__ a1,
    const float* __restrict__ W2, const float* __restrict__ a2,
    short* __restrict__ xb, unsigned int* __restrict__ adjp,
    short* __restrict__ Wencb,
    short* __restrict__ Wt1, short* __restrict__ We1,
    short* __restrict__ Wt2, short* __restrict__ We2,
    short* __restrict__ wc1t)
{
    const int blk = blockIdx.x, t = threadIdx.x;
    if (blk < 128) {
        const float* W = (blk < 64) ? W1 : W2;
        const float* a = (blk < 64) ? a1 : a2;
        short* Wt = (blk < 64) ? Wt1 : Wt2;
        short* We = (blk < 64) ? We1 : We2;
        const int idx = (blk & 63) * 256 + t;          // 0..16383
        const int h = idx >> 12, nn = (idx >> 7) & 31, k = idx & 127;
        Wt[idx] = bfb(W[k * HID + h * 32 + nn]);
        short wv = 0;
        if (nn < 2) {
            const float* ap = a + h * 64 + nn * 32;
            float s = 0.f;
#pragma unroll 8
            for (int d = 0; d < 32; ++d) s += W[k * HID + h * 32 + d] * ap[d];
            wv = bfb(s);
        }
        We[idx] = wv;
    } else if (blk < 192) {
        const int idx = (blk - 128) * 256 + t;         // 0..16383
        const int col = idx >> 7, k = idx & 127;
        Wencb[idx] = (k < IN_DIM) ? bfb(W_enc[(size_t)k * HID + col]) : (short)0;
    } else if (blk < 192 + BN_TOT / 4) {
        const int row = (blk - 192) * 4 + (t >> 6);    // b*116+i
        const int l = t & 63;
        const float v1 = adj[(size_t)row * N_NODES + l];
        const float v2 = (l < N_NODES - 64) ? adj[(size_t)row * N_NODES + 64 + l] : 0.f;
        const unsigned long long m1 = __ballot(v1 != 0.f);
        const unsigned long long m2 = __ballot(v2 != 0.f);
        if (l == 0) {
            uint4 v;
            v.x = (unsigned int)m1; v.y = (unsigned int)(m1 >> 32);
            v.z = (unsigned int)m2; v.w = (unsigned int)(m2 >> 32);
            *reinterpret_cast<uint4*>(&adjp[(size_t)row * 4]) = v;
        }
    } else if (blk < 192 + BN_TOT / 4 + (BN_TOT * 16) / 256) {
        // xprep: 16 threads per row, short8 writes
        const int i = (blk - (192 + BN_TOT / 4)) * 256 + t;
        const int row = i >> 4, kb = (i & 15) * 8;
        short8 v;
#pragma unroll
        for (int e = 0; e < 8; ++e) {
            const int k = kb + e;
            v[e] = (k < IN_DIM) ? bfb(x[(size_t)row * IN_DIM + k]) : (short)0;
        }
        *reinterpret_cast<short8*>(&xb[(size_t)row * 128 + kb]) = v;
    } else {
        // wc1prep: wc1t[n][k] = bf16(Wc1[k][n])
        const int idx = (blk - (192 + BN_TOT / 4 + (BN_TOT * 16) / 256)) * 256 + t;
        const int k = idx >> 8, n = idx & 255;
        wc1t[(size_t)n * FLAT_DIM + k] = bfb(Wc1[(size_t)k * 256 + n]);
    }
}

// ---------------- encoder via MFMA: hb0 = bf16(BN(elu(xb @ Wencb + b))) ---
__global__ __launch_bounds__(256) void enc_mfma(
    const short* __restrict__ xb, const short* __restrict__ Wencb,
    const float* __restrict__ bias,
    const float* __restrict__ g, const float* __restrict__ bta,
    const float* __restrict__ mn, const float* __restrict__ vr,
    short* __restrict__ houtb)
{
    const int t = threadIdx.x;
    const int lane = t & 63, w = t >> 6;
    const int half = lane >> 5, nn = lane & 31;
    const int row0 = blockIdx.x * 128 + w * 32;
    const short8* ap = reinterpret_cast<const short8*>(xb + (size_t)(row0 + nn) * 128);
    short8 af[8];
#pragma unroll
    for (int s = 0; s < 8; ++s) af[s] = ap[s * 2 + half];
#pragma unroll
    for (int ct = 0; ct < 4; ++ct) {
        const int col = ct * 32 + nn;
        const short8* bp = reinterpret_cast<const short8*>(Wencb + (size_t)col * 128);
        f32x16 acc = {};
#pragma unroll
        for (int s = 0; s < 8; ++s)
            acc = __builtin_amdgcn_mfma_f32_32x32x16_bf16(af[s], bp[s * 2 + half], acc, 0, 0, 0);
        const float bb = bias[col];
        const float gg = g[col], bbn = bta[col], mm = mn[col];
        const float rstd = rsqrtf(vr[col] + 1e-5f);
#pragma unroll
        for (int reg = 0; reg < 16; ++reg) {
            const int r = (reg & 3) + 8 * (reg >> 2) + 4 * half;
            float val = elu1(acc[reg] + bb);
            val = (val - mm) * rstd * gg + bbn;
            houtb[(size_t)(row0 + r) * HID + col] = bfb(val);
        }
    }
}

// ---------------- vn0 = vne + mean_n(h) (bf16 h) ----------------
__global__ __launch_bounds__(128) void vn0_kernel(
    const short* __restrict__ hb, const float* __restrict__ vne,
    float* __restrict__ vn)
{
    const int b = blockIdx.x, f = threadIdx.x;
    float s = 0.f;
    for (int n = 0; n < N_NODES; ++n)
        s += bf2f(hb[(size_t)(b * N_NODES + n) * HID + f]);
    vn[b * HID + f] = vne[f] + s * (1.f / N_NODES);
}

// ---------------- fused GAT layer (bf16 h I/O, instruction-dieted) --------
// L=0: A=hb0 -> h1b.  L=1: A=h1b, corr trick for +0.1vn, -> hb0 (final h).
template <int L>
__global__ __launch_bounds__(256, 4) void gat_fused(
    const short* __restrict__ hbin, short* __restrict__ houtb,
    const short* __restrict__ Wt, const short* __restrict__ Weij,
    const unsigned int* __restrict__ adjp,
    const float* __restrict__ g_, const float* __restrict__ bt_,
    const float* __restrict__ mn_, const float* __restrict__ vr_,
    const float* __restrict__ vn, const float* __restrict__ wcorr,
    const float* __restrict__ eicorr, float* __restrict__ premean)
{
    constexpr int KP = 136;   // s_p pitch (shorts)
    // declaration order matters: dead-row A-frag reads (rows 116..127 of s_p)
    // land inside s_whsT/s_eir — in-allocation garbage, C rows discarded.
    __shared__ __align__(16) __hip_bfloat16 s_p[N_NODES][KP];   // 31552 B
    __shared__ __align__(16) __hip_bfloat16 s_whsT[32][128];    // 8192 B, XOR-swizzled
    __shared__ float s_eir[232];                                // 928 B -> 40672 B

    const int t = threadIdx.x;
    const int n_ = blockIdx.x;
    const int b = (n_ & 7) * 64 + (n_ >> 5);
    const int h = (n_ >> 3) & 3;

    const int lane = t & 63, w = t >> 6;
    const int half = lane >> 5, nn = lane & 31;
    const int row = w * 32 + nn;
    const int hr = (row < N_NODES) ? row : 0;
    const int swz = (nn & 7) << 4;   // XOR swizzle for s_whsT (G4)

    // layer-2 correction terms (exact linearity: Wh(h+0.1v)=Wh·h + wcorr)
    float wc = 0.f, eic = 0.f, ejc = 0.f;
    if (L == 1) {
        wc = wcorr[(size_t)b * HID + h * 32 + nn];
        eic = eicorr[b * 8 + h * 2];
        ejc = eicorr[b * 8 + h * 2 + 1];
    }

    // ---- phase 1: Whs = h @ W-slice and [ei|ej] = h @ Weij, both MFMA ----
    {
        const short8* ap = reinterpret_cast<const short8*>(
            hbin + (size_t)(b * N_NODES + hr) * HID);
        const short8* wtp = reinterpret_cast<const short8*>(Wt + ((h * 32 + nn) << 7));
        const short8* wep = reinterpret_cast<const short8*>(Weij + ((h * 32 + nn) << 7));
        f32x16 wacc = {};
        f32x16 eacc = {};
#pragma unroll
        for (int s = 0; s < 8; ++s) {
            const int fi = s * 2 + half;
            const short8 af = ap[fi];
            wacc = __builtin_amdgcn_mfma_f32_32x32x16_bf16(af, wtp[fi], wacc, 0, 0, 0);
            eacc = __builtin_amdgcn_mfma_f32_32x32x16_bf16(af, wep[fi], eacc, 0, 0, 0);
        }
        // transposed scatter: s_whsT[nn][col] (swizzled) = Whs[col][nn]
        char* wbase = reinterpret_cast<char*>(&s_whsT[0][0]) + nn * 256;
#pragma unroll
        for (int reg = 0; reg < 16; ++reg) {
            const int r = (reg & 3) + 8 * (reg >> 2) + 4 * half;
            const int col = w * 32 + r;
            *reinterpret_cast<__hip_bfloat16*>(wbase + ((col * 2) ^ swz)) =
                __float2bfloat16(wacc[reg]);
        }
        if (nn == 0) {
#pragma unroll
            for (int reg = 0; reg < 16; ++reg) {
                const int r = w * 32 + (reg & 3) + 8 * (reg >> 2) + 4 * half;
                if (r < N_NODES) s_eir[r] = eacc[reg] + eic;
            }
        }
        if (nn == 1) {
#pragma unroll
            for (int reg = 0; reg < 16; ++reg) {
                const int r = w * 32 + (reg & 3) + 8 * (reg >> 2) + 4 * half;
                if (r < N_NODES) s_eir[N_NODES + r] = eacc[reg] + ejc;
            }
        }
    }
    __syncthreads();

    // ---- phase 2 (wave-local rows): unnormalized exp scores, col-pairs ----
    {
        const int l = lane;
        const int c0 = 2 * l;                  // this lane's columns c0, c0+1
        const bool valid = (c0 < N_NODES);     // cols >=116 are K-pad zeros
        const float ejl  = valid ? s_eir[N_NODES + c0] : 0.f;
        const float ejl2 = valid ? s_eir[N_NODES + c0 + 1] : 0.f;
        const int sh = c0 & 31;
        const int i0 = w * 32;
        const int cnt = (w < 3) ? 32 : 20;
        const uint4* ap = reinterpret_cast<const uint4*>(
            adjp + ((size_t)b * N_NODES + i0) * 4);
        char* prow0 = reinterpret_cast<char*>(&s_p[i0][0]) + c0 * 2;
#pragma unroll 4
        for (int ii = 0; ii < cnt; ++ii) {
            const uint4 aw = ap[ii];
            const unsigned int wa = (l & 16) ? aw.y : aw.x;
            const unsigned int wb = (l & 16) ? aw.w : aw.z;
            const unsigned int word = (l & 32) ? wb : wa;
            const unsigned int bits = word >> sh;
            const float eii = s_eir[i0 + ii];
            float e1 = eii + ejl;
            float e2 = eii + ejl2;
            e1 = fmaxf(e1, 0.2f * e1);         // leaky_relu
            e2 = fmaxf(e2, 0.2f * e2);
            const float x1 = ((bits & 1) && valid) ? __expf(e1) : 0.f;
            const float x2 = ((bits & 2) && valid) ? __expf(e2) : 0.f;
            unsigned int pk;
            asm("v_cvt_pk_bf16_f32 %0, %1, %2" : "=v"(pk) : "v"(x1), "v"(x2));
            *reinterpret_cast<unsigned int*>(prow0 + ii * (KP * 2)) = pk;
        }
    }
    // no barrier: phase 3 reads only this wave's s_p rows

    // ---- phase 3: MFMA — O = P_u @ Whs and rowsum = P_u @ ones ----
    float psum = 0.f;
    {
        f32x16 acc = {};
        f32x16 accs = {};
        short8 ones;
#pragma unroll
        for (int e = 0; e < 8; ++e) ones[e] = (short)0x3F80;
        const char* wbase = reinterpret_cast<const char*>(&s_whsT[0][0]) + nn * 256;
#pragma unroll
        for (int s = 0; s < 8; ++s) {
            const int k0 = s * 16 + half * 8;
            const short8 afrag = *reinterpret_cast<const short8*>(
                &s_p[0][0] + (size_t)row * KP + k0);
            const short8 bfrag = *reinterpret_cast<const short8*>(
                wbase + ((k0 * 2) ^ swz));
            acc = __builtin_amdgcn_mfma_f32_32x32x16_bf16(afrag, bfrag, acc, 0, 0, 0);
            accs = __builtin_amdgcn_mfma_f32_32x32x16_bf16(afrag, ones, accs, 0, 0, 0);
        }
        const int f = h * 32 + nn;
        const float G = g_[f], B = bt_[f], M = mn_[f];
        const float R = rsqrtf(vr_[f] + 1e-5f);
        const float vadd = (L == 1) ? 0.1f * vn[(size_t)b * HID + f] : 0.f;
        const char* wrb = reinterpret_cast<const char*>(&s_whsT[0][0]) + nn * 256;
#pragma unroll
        for (int reg = 0; reg < 16; ++reg) {
            const int r = (reg & 3) + 8 * (reg >> 2) + 4 * half;
            const int i = w * 32 + r;
            if (i < N_NODES) {
                const size_t off = ((size_t)b * N_NODES + i) * HID + f;
                const float aval = acc[reg] * __builtin_amdgcn_rcpf(accs[reg]) + wc;
                float xv = elu1((aval - M) * R * G + B);
                const float res = bf2f(*reinterpret_cast<const short*>(
                    wrb + ((i * 2) ^ swz)));
                float outv = xv + res + wc;
                if (L == 1) outv += bf2f(hbin[off]) + vadd;
                houtb[off] = bfb(outv);
                psum += outv;
            }
        }
    }
    psum += __shfl_xor(psum, 32);
    __syncthreads();                       // all waves done reading s_eir
    if (half == 0) s_eir[w * 32 + nn] = psum;
    __syncthreads();
    if (t < 32) {
        const float s = s_eir[t] + s_eir[32 + t] + s_eir[64 + t] + s_eir[96 + t];
        premean[(size_t)b * HID + h * 32 + t] = s * (1.f / N_NODES);
    }
}

// ---------------- vn MLP (+ corr emission for layer 2) --------------------
__global__ __launch_bounds__(128) void vn_mlp_kernel(
    const float* __restrict__ prev, const float* __restrict__ premean,
    const float* __restrict__ Wv, const float* __restrict__ bv,
    const float* __restrict__ W2, const float* __restrict__ a2,
    float* __restrict__ vout, float* __restrict__ wcorr,
    float* __restrict__ eicorr)
{
    __shared__ float cat[2 * HID];
    const int b = blockIdx.x, f = threadIdx.x;
    cat[f] = prev[b * HID + f];
    cat[HID + f] = premean[b * HID + f];
    __syncthreads();
    float acc = bv[f];
    for (int k = 0; k < 2 * HID; ++k) acc += cat[k] * Wv[k * HID + f];
    const float o = elu1(acc);
    vout[b * HID + f] = o;
    __syncthreads();
    cat[f] = o;                       // reuse as s_vnn
    __syncthreads();
    float wcf = 0.f;
#pragma unroll 4
    for (int k = 0; k < HID; ++k) wcf += cat[k] * W2[k * HID + f];
    wcf *= 0.1f;
    wcorr[(size_t)b * HID + f] = wcf;
    __syncthreads();
    cat[f] = wcf;                     // reuse as s_wcorr
    __syncthreads();
    if (f < 8) {
        const int h = f >> 1, sel = f & 1;
        float e = 0.f;
#pragma unroll 8
        for (int d = 0; d < 32; ++d)
            e += cat[h * 32 + d] * a2[h * 64 + sel * 32 + d];
        eicorr[b * 8 + f] = e;
    }
}

// ---------------- pooling + vnf MLP + net attention + flat + LayerNorm ----
__global__ __launch_bounds__(128) void pool_flat_kernel(
    const short* __restrict__ hb, const float* __restrict__ vnn,
    const float* __restrict__ pms2,
    const float* __restrict__ Wv, const float* __restrict__ bv,
    const float* __restrict__ pm,
    const float* __restrict__ Wa1, const float* __restrict__ ba1,
    const float* __restrict__ Wa2, const float* __restrict__ ba2,
    const float* __restrict__ ln_g, const float* __restrict__ ln_b,
    float* __restrict__ out, short* __restrict__ flatb)
{
    __shared__ float s_pm[N_NODES * 9];
    __shared__ float s_v[2 * HID];
    __shared__ float s_p[9][HID];
    __shared__ float s_s[9];
    __shared__ float s_red[4];
    const int b = blockIdx.x, f = threadIdx.x;
    for (int idx = f; idx < N_NODES * 9; idx += 128) s_pm[idx] = pm[idx];
    s_v[f] = vnn[b * HID + f];
    s_v[HID + f] = pms2[b * HID + f];
    __syncthreads();
    float vacc = bv[f];
    for (int k = 0; k < 2 * HID; ++k) vacc += s_v[k] * Wv[k * HID + f];
    const float vnf_f = elu1(vacc);
    float p[9] = {};
    for (int n = 0; n < N_NODES; ++n) {
        const float hv = bf2f(hb[(size_t)b * HROW + n * HID + f]);
#pragma unroll
        for (int k = 0; k < 9; ++k) p[k] += s_pm[n * 9 + k] * hv;
    }
#pragma unroll
    for (int k = 0; k < 9; ++k) s_p[k][f] = p[k];
    __syncthreads();
    for (int pass = 0; pass < 3; ++pass) {
        const int k = pass * 4 + (f >> 5);
        if (k < 9) {
            const int j = f & 31;
            float z = ba1[j];
            for (int d = 0; d < HID; ++d) z += s_p[k][d] * Wa1[d * 32 + j];
            z = tanhf(z);
            float part = z * Wa2[j];
#pragma unroll
            for (int off = 16; off; off >>= 1) part += __shfl_xor(part, off);
            if (j == 0) s_s[k] = part + ba2[0];
        }
    }
    __syncthreads();
    float smax = -1e30f;
#pragma unroll
    for (int k = 0; k < 9; ++k) smax = fmaxf(smax, s_s[k]);
    float wgt[9], ssum = 0.f;
#pragma unroll
    for (int k = 0; k < 9; ++k) { wgt[k] = expf(s_s[k] - smax); ssum += wgt[k]; }
    const float sinv = 1.f / ssum;
    float vals[10];
#pragma unroll
    for (int k = 0; k < 9; ++k) vals[k] = p[k] * wgt[k] * sinv;
    vals[9] = vnf_f;
    float lsum = 0.f, lsq = 0.f;
#pragma unroll
    for (int q = 0; q < 10; ++q) { lsum += vals[q]; lsq += vals[q] * vals[q]; }
#pragma unroll
    for (int off = 32; off; off >>= 1) {
        lsum += __shfl_xor(lsum, off);
        lsq += __shfl_xor(lsq, off);
    }
    const int lane = f & 63, wid = f >> 6;
    if (lane == 0) { s_red[wid * 2] = lsum; s_red[wid * 2 + 1] = lsq; }
    __syncthreads();
    const float tot = s_red[0] + s_red[2];
    const float totsq = s_red[1] + s_red[3];
    const float mean = tot * (1.f / FLAT_DIM);
    const float var = totsq * (1.f / FLAT_DIM) - mean * mean;
    const float rstd = rsqrtf(var + 1e-5f);
    float* fout = out + 1024 + (size_t)b * FLAT_DIM;
    short* fb = flatb + (size_t)b * FLAT_DIM;
#pragma unroll
    for (int k = 0; k < 9; ++k) {
        const int j = k * HID + f;
        const float v = (vals[k] - mean) * rstd * ln_g[j] + ln_b[j];
        fout[j] = v;
        fb[j] = bfb(v);
    }
    const int j = 9 * HID + f;
    const float v9 = (vals[9] - mean) * rstd * ln_g[j] + ln_b[j];
    fout[j] = v9;
    fb[j] = bfb(v9);
}

// ---------------- classifier stage 1: one wave per 32x32 tile -------------
__global__ __launch_bounds__(64) void cls_mm_kernel(
    const short* __restrict__ flatb, const short* __restrict__ wc1t,
    const float* __restrict__ bc1, float* __restrict__ hid)
{
    const int lane = threadIdx.x;
    const int half = lane >> 5, nn = lane & 31;
    const int mt = blockIdx.x >> 3;
    const int ct = blockIdx.x & 7;
    const int r0 = mt * 32;
    const int c0 = ct * 32;
    const short8* ap = reinterpret_cast<const short8*>(flatb + (size_t)(r0 + nn) * FLAT_DIM);
    const short8* bp = reinterpret_cast<const short8*>(wc1t + (size_t)(c0 + nn) * FLAT_DIM);
    f32x16 acc = {};
#pragma unroll 8
    for (int s = 0; s < 80; ++s) {
        const int fi = s * 2 + half;
        acc = __builtin_amdgcn_mfma_f32_32x32x16_bf16(ap[fi], bp[fi], acc, 0, 0, 0);
    }
    const float bb = bc1[c0 + nn];
#pragma unroll
    for (int reg = 0; reg < 16; ++reg) {
        const int row = (reg & 3) + 8 * (reg >> 2) + 4 * half;
        hid[(size_t)(r0 + row) * 256 + c0 + nn] = elu1(acc[reg] + bb);
    }
}

// ---------------- classifier stage 2: logits = hid @ Wc2 + bc2 (f32) ------
__global__ __launch_bounds__(256) void logits_kernel(
    const float* __restrict__ hid, const float* __restrict__ Wc2,
    const float* __restrict__ bc2, float* __restrict__ out)
{
    const int idx = blockIdx.x * 256 + threadIdx.x;  // 0..1023
    const int row = idx >> 1, c = idx & 1;
    const float4* hp = reinterpret_cast<const float4*>(hid + (size_t)row * 256);
    float acc = 0.f;
#pragma unroll 8
    for (int q = 0; q < 64; ++q) {
        const float4 hv = hp[q];
        acc += hv.x * Wc2[(q * 4 + 0) * 2 + c] + hv.y * Wc2[(q * 4 + 1) * 2 + c]
             + hv.z * Wc2[(q * 4 + 2) * 2 + c] + hv.w * Wc2[(q * 4 + 3) * 2 + c];
    }
    out[idx] = acc + bc2[c];
}

extern "C" void kernel_launch(void* const* d_in, const int* in_sizes, int n_in,
                              void* d_out, int out_size, void* d_ws, size_t ws_size,
                              hipStream_t stream)
{
    const float* x     = (const float*)d_in[0];
    const float* adj   = (const float*)d_in[1];
    const float* W_enc = (const float*)d_in[2];
    const float* b_enc = (const float*)d_in[3];
    const float* bn_g  = (const float*)d_in[4];
    const float* bn_b  = (const float*)d_in[5];
    const float* bn_m  = (const float*)d_in[6];
    const float* bn_v  = (const float*)d_in[7];
    const float* vne   = (const float*)d_in[8];
    const float* W1    = (const float*)d_in[9];
    const float* a1    = (const float*)d_in[10];
    const float* g1    = (const float*)d_in[11];
    const float* bt1   = (const float*)d_in[12];
    const float* m1    = (const float*)d_in[13];
    const float* v1    = (const float*)d_in[14];
    const float* W2    = (const float*)d_in[15];
    const float* a2    = (const float*)d_in[16];
    const float* g2    = (const float*)d_in[17];
    const float* bt2   = (const float*)d_in[18];
    const float* m2    = (const float*)d_in[19];
    const float* v2    = (const float*)d_in[20];
    const float* Wv    = (const float*)d_in[21];
    const float* bv    = (const float*)d_in[22];
    const float* pm    = (const float*)d_in[23];
    const float* Wa1   = (const float*)d_in[24];
    const float* ba1   = (const float*)d_in[25];
    const float* Wa2   = (const float*)d_in[26];
    const float* ba2   = (const float*)d_in[27];
    const float* ln_g  = (const float*)d_in[28];
    const float* ln_b  = (const float*)d_in[29];
    const float* Wc1   = (const float*)d_in[30];
    const float* bc1   = (const float*)d_in[31];
    const float* Wc2   = (const float*)d_in[32];
    const float* bc2   = (const float*)d_in[33];
    float* out = (float*)d_out;

    // region1 (30.4 MB): xb (dead after enc) -> flatb (pool output)
    char* ws = (char*)d_ws;
    short* xb    = (short*)ws;
    short* flatb = (short*)ws;
    short* hb0  = (short*)(ws + (size_t)BN_TOT * HID * 4);  // enc out, then final h
    short* h1b  = hb0 + (size_t)BN_TOT * HID;               // gat1 out
    float* tail = (float*)(h1b + (size_t)BN_TOT * HID);
    float* vn0g = tail;
    float* vnn  = vn0g + BATCH * HID;
    float* pms1 = vnn + BATCH * HID;
    float* pms2 = pms1 + BATCH * HID;
    float* wcorr = pms2 + BATCH * HID;
    float* eicorr = wcorr + BATCH * HID;
    unsigned int* adjp = (unsigned int*)(eicorr + BATCH * 8);
    short* Wt1  = (short*)(adjp + (size_t)BN_TOT * 4);
    short* We1  = Wt1 + 16384;
    short* Wt2  = We1 + 16384;
    short* We2  = Wt2 + 16384;
    short* Wencb = We2 + 16384;
    short* wc1t = Wencb + 16384;                            // 327,680 shorts
    float* hid  = (float*)(wc1t + 256 * FLAT_DIM);          // 131,072 floats

    // merged prep (Wt/Weij, Wencb, adjpack, xprep, wc1prep)
    const int prep_blocks = 192 + BN_TOT / 4 + (BN_TOT * 16) / 256 + 1280;
    prep_all<<<prep_blocks, 256, 0, stream>>>(x, adj, W_enc, Wc1, W1, a1, W2, a2,
                                              xb, adjp, Wencb, Wt1, We1, Wt2, We2,
                                              wc1t);
    // encoder: xb -> hb0 (bf16)
    enc_mfma<<<BN_TOT / 128, 256, 0, stream>>>(xb, Wencb, b_enc, bn_g, bn_b,
                                               bn_m, bn_v, hb0);
    vn0_kernel<<<BATCH, 128, 0, stream>>>(hb0, vne, vn0g);
    // GAT layer 1: hb0 -> h1b (bf16)
    gat_fused<0><<<BATCH * HEADS, 256, 0, stream>>>(
        hb0, h1b, Wt1, We1, adjp, g1, bt1, m1, v1,
        nullptr, nullptr, nullptr, pms1);
    // vn MLP + layer-2 correction terms
    vn_mlp_kernel<<<BATCH, 128, 0, stream>>>(vn0g, pms1, Wv, bv, W2, a2,
                                             vnn, wcorr, eicorr);
    // GAT layer 2: h1b -> hb0 (final h, bf16)
    gat_fused<1><<<BATCH * HEADS, 256, 0, stream>>>(
        h1b, hb0, Wt2, We2, adjp, g2, bt2, m2, v2,
        vnn, wcorr, eicorr, pms2);
    // pooling + fused vnf + flat + LayerNorm (writes out[1024:] and flatb)
    pool_flat_kernel<<<BATCH, 128, 0, stream>>>(hb0, vnn, pms2, Wv, bv, pm,
                                                Wa1, ba1, Wa2, ba2,
                                                ln_g, ln_b, out, flatb);
    // classifier: MFMA GEMM (128 waves) + tiny logits pass
    cls_mm_kernel<<<128, 64, 0, stream>>>(flatb, wc1t, bc1, hid);
    logits_kernel<<<4, 256, 0, stream>>>(hid, Wc2, bc2, out);
}